// Round 8
// baseline (172.307 us; speedup 1.0000x reference)
//
#include <hip/hip_runtime.h>
#include <hip/hip_bf16.h>

// Problem constants
#define B_  16
#define N_  512
#define M_  16
#define H_  8
#define D_  128
#define BN_ 8192   // B_*N_
#define NB  16     // nodes per block in main kernel

typedef __attribute__((ext_vector_type(4))) float          f32x4;
typedef __attribute__((ext_vector_type(2))) _Float16       f16x2;
typedef __attribute__((ext_vector_type(4))) _Float16       f16x4;
typedef __attribute__((ext_vector_type(8))) unsigned short u16x8;
typedef __attribute__((ext_vector_type(8))) _Float16       f16x8;

static __device__ __forceinline__ float bf2f(__hip_bfloat16 x) { return __bfloat162float(x); }
static __device__ __forceinline__ unsigned short f2bu(float x) {
    __hip_bfloat16 b = __float2bfloat16(x);
    return *reinterpret_cast<unsigned short*>(&b);
}
static __device__ __forceinline__ float bu2f(unsigned short u) {
    return __uint_as_float(((unsigned int)u) << 16);
}

// Load/store policy: interpret float tensors as f32 or bf16.
template <bool F32>
struct Pol {
    static __device__ __forceinline__ float ld(const void* p, int i) {
        if constexpr (F32) return ((const float*)p)[i];
        else               return bf2f(((const __hip_bfloat16*)p)[i]);
    }
    static __device__ __forceinline__ float2 ld2(const void* p, long i) {  // i%2==0
        if constexpr (F32) return *(const float2*)((const float*)p + i);
        else {
            const ushort2 u = *(const ushort2*)((const unsigned short*)p + i);
            return make_float2(bu2f(u.x), bu2f(u.y));
        }
    }
    static __device__ __forceinline__ float4 ld4(const void* p, int i) {  // i%4==0
        if constexpr (F32) return *(const float4*)((const float*)p + i);
        else {
            const ushort4 u = *(const ushort4*)((const unsigned short*)p + i);
            return make_float4(bu2f(u.x), bu2f(u.y), bu2f(u.z), bu2f(u.w));
        }
    }
    static __device__ __forceinline__ void ld8(const void* p, long i, float* v) {  // i%8==0
        if constexpr (F32) {
            const float4 a = *(const float4*)((const float*)p + i);
            const float4 b = *(const float4*)((const float*)p + i + 4);
            v[0]=a.x; v[1]=a.y; v[2]=a.z; v[3]=a.w;
            v[4]=b.x; v[5]=b.y; v[6]=b.z; v[7]=b.w;
        } else {
            const u16x8 u = *(const u16x8*)((const unsigned short*)p + i);
            #pragma unroll
            for (int j = 0; j < 8; ++j) v[j] = bu2f(u[j]);
        }
    }
    static __device__ __forceinline__ void st8(void* p, long i, const float* v) {  // i%8==0
        if constexpr (F32) {
            *(float4*)((float*)p + i)     = make_float4(v[0], v[1], v[2], v[3]);
            *(float4*)((float*)p + i + 4) = make_float4(v[4], v[5], v[6], v[7]);
        } else {
            u16x8 u;
            #pragma unroll
            for (int j = 0; j < 8; ++j) u[j] = f2bu(v[j]);
            *(u16x8*)((unsigned short*)p + i) = u;
        }
    }
};

// Dtype probe (verbatim): f32 buffers read as bf16 at even index give
// random-exponent garbage; genuine bf16 stays small.
static __device__ __forceinline__ bool probe_is_f32(const void* h) {
    bool is_f32 = false;
    const __hip_bfloat16* hb = (const __hip_bfloat16*)h;
    for (int i = 0; i < 128; ++i) {
        const float v = bf2f(hb[2 * i]);
        if (!(fabsf(v) < 1e4f)) is_f32 = true;
    }
    return is_f32;
}

// ---------------------------------------------------------------------------
// k0s (grid 8, 256 thr): wsrc/wdst[h][d] = sum_e W[h][d][e]*a_{src,dst}[h][e]
// [verbatim round-5 k0 else-branch, hh = blockIdx.x]
// ---------------------------------------------------------------------------
template <bool F32>
static __device__ __forceinline__ void k0s_body(
        const void* __restrict__ W, const void* __restrict__ a_src,
        const void* __restrict__ a_dst,
        float* __restrict__ wsrc, float* __restrict__ wdst) {
    using P = Pol<F32>;
    const int hh = blockIdx.x;
    const int t  = threadIdx.x;
    const int which = t >> 7, d = t & 127;
    const void* av = which ? a_dst : a_src;
    const int wbase = hh * (D_ * D_) + d * 128;
    float acc = 0.f;
    #pragma unroll 8
    for (int e = 0; e < 128; e += 4) {
        const float4 wv = P::ld4(W, wbase + e);
        const float4 aa = P::ld4(av, hh * 128 + e);
        acc += wv.x * aa.x + wv.y * aa.y + wv.z * aa.z + wv.w * aa.w;
    }
    (which ? wdst : wsrc)[hh * 128 + d] = acc;
}

__global__ __launch_bounds__(256) void k0s(
        const void* W, const void* a_src, const void* a_dst, const void* h,
        float* wsrc, float* wdst) {
    if (probe_is_f32(h)) k0s_body<true >(W, a_src, a_dst, wsrc, wdst);
    else                 k0s_body<false>(W, a_src, a_dst, wsrc, wdst);
}

// ---------------------------------------------------------------------------
// kB (grid 1024 or 1026, 256 thr) — merged medium kernels:
//   blk <  512 : WeffT[o][hd] = f16(sum_e W[hd][e]*Wo[(h*128+e)][o])  [proven]
//   blk < 1024 : scores for nodes (blk-512)*16  [round-5 k1, verbatim]
//   blk ==1024 : w1T[o][k] = f16(w1[k][o])   [256x128]
//   blk ==1025 : w2T[o][k] = f16(w2[k][o])   [128x256]
// ---------------------------------------------------------------------------
template <bool F32>
static __device__ __forceinline__ void kB_body(
        const void* __restrict__ W,  const void* __restrict__ Wo,
        const void* __restrict__ h,
        const float* __restrict__ wsrc, const float* __restrict__ wdst,
        const void* __restrict__ w1, const void* __restrict__ w2,
        _Float16* __restrict__ WeffT,
        _Float16* __restrict__ ssrc_h, _Float16* __restrict__ sdst_h,
        _Float16* __restrict__ w1T, _Float16* __restrict__ w2T,
        float* sbuf /* shared [2*16*132] */) {
    using P = Pol<F32>;
    const int blk = blockIdx.x;
    const int t   = threadIdx.x;
    if (blk < 512) {
        // ---- Weff (proven round-5 code) ----
        float* wrow = sbuf;
        const int half = t >> 7, o = t & 127;
        const int hd = blk * 2 + half;               // hd = h*128 + d
        wrow[half * 128 + o] = P::ld(W, hd * 128 + o);
        __syncthreads();
        const int hh = hd >> 7;
        float acc = 0.f;
        #pragma unroll 8
        for (int e = 0; e < 128; ++e)
            acc += wrow[half * 128 + e] * P::ld(Wo, (hh * 128 + e) * 128 + o);
        WeffT[(size_t)o * 1024 + hd] = (_Float16)acc;
    } else if (blk < 1024) {
        // ---- scores (proven round-5 k1 body) ----
        float* hls = sbuf;               // [16][132]
        float* wls = sbuf + 16 * 132;    // [16][132]
        const int bn0 = (blk - 512) * 16;
        {
            const int r = t >> 4, c0 = (t & 15) * 8;
            float v[8];
            P::ld8(h, (long)(bn0 + r) * 128 + c0, v);
            #pragma unroll
            for (int j = 0; j < 8; ++j) hls[r * 132 + c0 + j] = v[j];
            const int c = t >> 4;                    // c = which*8 + head
            const float* wp = (c >> 3) ? wdst : wsrc;
            const int woff = (c & 7) * 128 + c0;
            #pragma unroll
            for (int j = 0; j < 8; ++j) wls[c * 132 + c0 + j] = wp[woff + j];
        }
        __syncthreads();
        const int n = t >> 4, c = t & 15;
        float acc = 0.f;
        #pragma unroll
        for (int e = 0; e < 128; e += 4) {
            const float4 hv = *(const float4*)(hls + n * 132 + e);
            const float4 wv = *(const float4*)(wls + c * 132 + e);
            acc += hv.x * wv.x + hv.y * wv.y + hv.z * wv.z + hv.w * wv.w;
        }
        const int node = bn0 + n;
        if (c < 8) ssrc_h[node * 8 + c]       = (_Float16)acc;
        else       sdst_h[node * 8 + (c - 8)] = (_Float16)acc;
    } else if (blk == 1024) {
        // ---- w1T transpose ----
        const int o = t;                              // 0..255
        for (int k0 = 0; k0 < 128; k0 += 8) {
            f16x8 v;
            #pragma unroll
            for (int j = 0; j < 8; ++j) v[j] = (_Float16)P::ld(w1, (k0 + j) * 256 + o);
            *(f16x8*)(w1T + o * 128 + k0) = v;
        }
    } else {
        // ---- w2T transpose ----
        const int o = t & 127, kh = t >> 7;
        for (int k0 = kh * 128; k0 < kh * 128 + 128; k0 += 8) {
            f16x8 v;
            #pragma unroll
            for (int j = 0; j < 8; ++j) v[j] = (_Float16)P::ld(w2, (k0 + j) * 128 + o);
            *(f16x8*)(w2T + o * 256 + k0) = v;
        }
    }
}

__global__ __launch_bounds__(256) void kB(
        const void* W, const void* Wo, const void* h,
        const float* wsrc, const float* wdst,
        const void* w1, const void* w2,
        _Float16* WeffT, _Float16* ssrc_h, _Float16* sdst_h,
        _Float16* w1T, _Float16* w2T) {
    __shared__ float sbuf[2 * 16 * 132];
    if (probe_is_f32(h))
        kB_body<true >(W, Wo, h, wsrc, wdst, w1, w2, WeffT, ssrc_h, sdst_h, w1T, w2T, sbuf);
    else
        kB_body<false>(W, Wo, h, wsrc, wdst, w1, w2, WeffT, ssrc_h, sdst_h, w1T, w2T, sbuf);
}

// ---------------------------------------------------------------------------
// Main fused kernel. 16 nodes/block, 512 threads (8 waves), grid 512.
// [round-5 structure — best measured 58.2 us — with one change: when TW,
//  FF1/FF2 B-fragments come from pre-transposed w1T/w2T as single 8-B vector
//  loads, PREFETCHED into registers before G1 so FF sees no B-load latency.]
// MFMA layout (proven): A lane(lo,hi) reg j = A[lo][4*hi+j]; B = B[4*hi+j][lo];
// D reg q -> row 4*hi+q, col lo.
// ---------------------------------------------------------------------------
struct __align__(16) Smem {
    union {
        _Float16 Zh[NB][1024];                 // 32768   P4 -> G1 (f16, swizzled)
        struct {
            float    ts[NB][132];              // 8448    LN1 -> FF1/FF2 (padded)
            _Float16 us[NB][260];              // 8320    FF1 -> FF2 (padded)
            float    ys[NB][128];              // 8192    FF2 -> LN2
        } ff;
    } u;
    float hs[NB][128];                         // 8192    residual
    union {
        float attn[NB][16][8];                 // 8192    P2 -> P4
        float yln[NB][128];                    // 8192    G1 -> LN1
    } v;
    int   nls[NB][16];                         // 1024
    int   adjs[NB][16];                        // 1024
    float ssrc[NB][8];                         // 512
};

template <bool F32, bool TW>
static __device__ __forceinline__ void gat_body(
        Smem& s,
        const void* __restrict__ h,
        const int*  __restrict__ adj,
        const int*  __restrict__ n_list,
        const _Float16* __restrict__ ssrc_h,
        const _Float16* __restrict__ sdst_h,
        const _Float16* __restrict__ WeffT,
        const _Float16* __restrict__ w1T,
        const _Float16* __restrict__ w2T,
        const void* __restrict__ g1, const void* __restrict__ bb1,
        const void* __restrict__ w1, const void* __restrict__ fb1,
        const void* __restrict__ w2, const void* __restrict__ fb2,
        const void* __restrict__ g2, const void* __restrict__ bb2,
        void* __restrict__ out) {
    using P = Pol<F32>;
    const int t   = threadIdx.x;
    const int bn0 = blockIdx.x * NB;
    const int b   = bn0 >> 9;                  // 512 nodes per batch
    const int l   = t & 63;
    const int w   = t >> 6;                    // wave 0..7
    const int lo  = l & 15;
    const int hi  = l >> 4;

    // ---- P1: self rows + neighbor lists + gathered ssrc  (512 threads)
    {
        const int r = t >> 5, c0 = (t & 31) * 4;
        const float4 v = P::ld4(h, (bn0 + r) * 128 + c0);
        *(float4*)&s.hs[r][c0] = v;
    }
    if (t < 256) {
        const int r = t >> 4, m = t & 15;
        s.nls[r][m]  = n_list[(bn0 + r) * M_ + m] & (N_ - 1);
        s.adjs[r][m] = adj[(bn0 + r) * M_ + m];
    }
    if (t < NB * 8) s.ssrc[t >> 3][t & 7] = (float)ssrc_h[bn0 * 8 + t];
    __syncthreads();

    // ---- P2: scores = mask(leaky(s_src + s_dst[nl]))   (256 threads)
    if (t < 256) {
        const int r = t >> 4, m = t & 15;
        const int nbr = s.nls[r][m];
        const f16x8 sd = *(const f16x8*)(sdst_h + (size_t)(b * N_ + nbr) * 8);
        const int amask = s.adjs[r][m];
        float sc[8];
        #pragma unroll
        for (int hh = 0; hh < 8; ++hh) {
            float x = s.ssrc[r][hh] + (float)sd[hh];
            x = x > 0.f ? x : 0.2f * x;        // leaky_relu BEFORE mask (ref order)
            if (amask == 0) x = -1e9f;
            sc[hh] = x;
        }
        *(float4*)&s.v.attn[r][m][0] = make_float4(sc[0], sc[1], sc[2], sc[3]);
        *(float4*)&s.v.attn[r][m][4] = make_float4(sc[4], sc[5], sc[6], sc[7]);
    }
    __syncthreads();

    // ---- P3: softmax over m   (128 threads)
    if (t < NB * 8) {
        const int r = t >> 3, hh = t & 7;
        float mx = -3.4e38f;
        #pragma unroll
        for (int m = 0; m < 16; ++m) mx = fmaxf(mx, s.v.attn[r][m][hh]);
        float ex[16], sum = 0.f;
        #pragma unroll
        for (int m = 0; m < 16; ++m) { ex[m] = __expf(s.v.attn[r][m][hh] - mx); sum += ex[m]; }
        const float inv = 1.f / sum;
        #pragma unroll
        for (int m = 0; m < 16; ++m) s.v.attn[r][m][hh] = ex[m] * inv;
    }
    __syncthreads();

    // ---- P4: Z[r][hh][d] = sum_m attn[r][m][hh] * h[nl[r][m]][d]
    //      512 threads: 32 threads/node, 4 d each.  (f16, swizzled)
    {
        const int r = t >> 5, dc = t & 31, d0 = dc * 4;
        float z[8][4];
        #pragma unroll
        for (int hh = 0; hh < 8; ++hh)
            #pragma unroll
            for (int jj = 0; jj < 4; ++jj) z[hh][jj] = 0.f;
        #pragma unroll 4
        for (int m = 0; m < 16; ++m) {
            const int nbr = s.nls[r][m];
            const float4 hv = P::ld4(h, (b * N_ + nbr) * 128 + d0);
            const float hv4[4] = { hv.x, hv.y, hv.z, hv.w };
            const float4 a0 = *(const float4*)&s.v.attn[r][m][0];
            const float4 a1 = *(const float4*)&s.v.attn[r][m][4];
            const float av[8] = { a0.x, a0.y, a0.z, a0.w, a1.x, a1.y, a1.z, a1.w };
            #pragma unroll
            for (int hh = 0; hh < 8; ++hh)
                #pragma unroll
                for (int jj = 0; jj < 4; ++jj) z[hh][jj] += av[hh] * hv4[jj];
        }
        char* zb = (char*)&s.u.Zh[0][0] + r * 2048;
        const int xo = (r & 7) << 4;
        #pragma unroll
        for (int hh = 0; hh < 8; ++hh) {
            f16x4 vv;
            #pragma unroll
            for (int jj = 0; jj < 4; ++jj) vv[jj] = (_Float16)z[hh][jj];
            *(f16x4*)(zb + ((hh * 256 + dc * 8) ^ xo)) = vv;
        }
    }
    __syncthreads();

    // ---- Prefetch FF1/FF2 B-fragments (TW only; independent of all LDS) ----
    f16x4 pb1[8][2];
    f16x4 pb2[16];
    if constexpr (TW) {
        #pragma unroll
        for (int ks = 0; ks < 8; ++ks)
            #pragma unroll
            for (int nt = 0; nt < 2; ++nt)
                pb1[ks][nt] = *(const f16x4*)(w1T + (size_t)(w * 32 + nt * 16 + lo) * 128
                                              + ks * 16 + hi * 4);
        #pragma unroll
        for (int ks = 0; ks < 16; ++ks)
            pb2[ks] = *(const f16x4*)(w2T + (size_t)(w * 16 + lo) * 256 + ks * 16 + hi * 4);
    }

    // ---- G1: yln = Zh @ WeffT^T + hs   (MFMA 16x16x16, K=1024; 8 waves x 16 cols)
    {
        const char* za  = (const char*)&s.u.Zh[0][0] + lo * 2048;
        const int   xo  = (lo & 7) << 4;
        const char* wb0 = (const char*)(WeffT + (size_t)(w * 16 + lo) * 1024);
        f32x4 acc0 = {0.f, 0.f, 0.f, 0.f};
        #pragma unroll 8
        for (int ks = 0; ks < 64; ++ks) {
            const int kb = ks * 32 + hi * 8;           // byte offset of k = ks*16 + hi*4
            const f16x4 a  = *(const f16x4*)(za + (kb ^ xo));
            const f16x4 b0 = *(const f16x4*)(wb0 + kb);
            acc0 = __builtin_amdgcn_mfma_f32_16x16x16f16(a, b0, acc0, 0, 0, 0);
        }
        const int o0 = w * 16 + lo;
        #pragma unroll
        for (int q = 0; q < 4; ++q) {
            const int rr = hi * 4 + q;
            s.v.yln[rr][o0] = acc0[q] + s.hs[rr][o0];
        }
    }
    __syncthreads();

    // ---- LN1 -> ts (f32, padded rows). 16 threads per row (256 threads).
    if (t < NB * 16) {
        const int r = t >> 4, j0 = (t & 15) * 8;
        const float4 x0 = *(const float4*)&s.v.yln[r][j0];
        const float4 x1 = *(const float4*)&s.v.yln[r][j0 + 4];
        const float x[8] = { x0.x, x0.y, x0.z, x0.w, x1.x, x1.y, x1.z, x1.w };
        float sm = 0.f, ss = 0.f;
        #pragma unroll
        for (int j = 0; j < 8; ++j) { sm += x[j]; ss += x[j] * x[j]; }
        #pragma unroll
        for (int off = 8; off > 0; off >>= 1) {
            sm += __shfl_xor(sm, off);
            ss += __shfl_xor(ss, off);
        }
        const float mu   = sm * (1.f / 128.f);
        const float var  = ss * (1.f / 128.f) - mu * mu;
        const float rstd = rsqrtf(var + 1e-5f);
        float gv[8], bv[8];
        P::ld8(g1, j0, gv);
        P::ld8(bb1, j0, bv);
        #pragma unroll
        for (int j = 0; j < 8; ++j)
            s.u.ff.ts[r][j0 + j] = (x[j] - mu) * rstd * gv[j] + bv[j];
    }
    __syncthreads();

    // ---- FF1: us = relu(ts @ w1 + b1)  (MFMA; 8 waves x 32 cols; K=128)
    {
        f32x4 acc[2] = { {0.f,0.f,0.f,0.f}, {0.f,0.f,0.f,0.f} };
        #pragma unroll
        for (int ks = 0; ks < 8; ++ks) {
            const int k = ks * 16 + hi * 4;
            const float4 tv = *(const float4*)&s.u.ff.ts[lo][k];
            f16x4 a;
            a[0] = (_Float16)tv.x; a[1] = (_Float16)tv.y;
            a[2] = (_Float16)tv.z; a[3] = (_Float16)tv.w;
            #pragma unroll
            for (int nt = 0; nt < 2; ++nt) {
                f16x4 bb;
                if constexpr (TW) {
                    bb = pb1[ks][nt];
                } else {
                    const int o = w * 32 + nt * 16 + lo;
                    #pragma unroll
                    for (int j = 0; j < 4; ++j) bb[j] = (_Float16)P::ld(w1, (k + j) * 256 + o);
                }
                acc[nt] = __builtin_amdgcn_mfma_f32_16x16x16f16(a, bb, acc[nt], 0, 0, 0);
            }
        }
        if (hi < 4) {
            #pragma unroll
            for (int nt = 0; nt < 2; ++nt) {
                const int o = w * 32 + nt * 16 + lo;
                const float bias = P::ld(fb1, o);
                #pragma unroll
                for (int q = 0; q < 4; ++q)
                    s.u.ff.us[hi * 4 + q][o] = (_Float16)fmaxf(acc[nt][q] + bias, 0.f);
            }
        }
    }
    __syncthreads();

    // ---- FF2: ys = us @ w2 + b2 + ts  (MFMA; 8 waves x 16 cols; K=256)
    {
        const int o0 = w * 16 + lo;
        f32x4 acc = {0.f, 0.f, 0.f, 0.f};
        #pragma unroll
        for (int ks = 0; ks < 16; ++ks) {
            const int k = ks * 16 + hi * 4;
            const f16x4 a = *(const f16x4*)&s.u.ff.us[lo][k];
            f16x4 bb;
            if constexpr (TW) {
                bb = pb2[ks];
            } else {
                #pragma unroll
                for (int j = 0; j < 4; ++j) bb[j] = (_Float16)P::ld(w2, (k + j) * 128 + o0);
            }
            acc = __builtin_amdgcn_mfma_f32_16x16x16f16(a, bb, acc, 0, 0, 0);
        }
        const float bias = P::ld(fb2, o0);
        #pragma unroll
        for (int q = 0; q < 4; ++q) {
            const int rr = hi * 4 + q;
            s.u.ff.ys[rr][o0] = acc[q] + bias + s.u.ff.ts[rr][o0];
        }
    }
    __syncthreads();

    // ---- LN2 -> out. 16 threads per row (256 threads).
    if (t < NB * 16) {
        const int r = t >> 4, j0 = (t & 15) * 8;
        const float4 x0 = *(const float4*)&s.u.ff.ys[r][j0];
        const float4 x1 = *(const float4*)&s.u.ff.ys[r][j0 + 4];
        const float x[8] = { x0.x, x0.y, x0.z, x0.w, x1.x, x1.y, x1.z, x1.w };
        float sm = 0.f, ss = 0.f;
        #pragma unroll
        for (int j = 0; j < 8; ++j) { sm += x[j]; ss += x[j] * x[j]; }
        #pragma unroll
        for (int off = 8; off > 0; off >>= 1) {
            sm += __shfl_xor(sm, off);
            ss += __shfl_xor(ss, off);
        }
        const float mu   = sm * (1.f / 128.f);
        const float var  = ss * (1.f / 128.f) - mu * mu;
        const float rstd = rsqrtf(var + 1e-5f);
        float gv[8], bv[8], o8[8];
        P::ld8(g2, j0, gv);
        P::ld8(bb2, j0, bv);
        #pragma unroll
        for (int j = 0; j < 8; ++j) o8[j] = (x[j] - mu) * rstd * gv[j] + bv[j];
        P::st8(out, (long)(bn0 + r) * 128 + j0, o8);
    }
}

template <bool TW>
__global__ __launch_bounds__(512, 4) void k_gat(
        const void* __restrict__ h,
        const int*  __restrict__ adj,
        const int*  __restrict__ n_list,
        const _Float16* __restrict__ ssrc_h,
        const _Float16* __restrict__ sdst_h,
        const _Float16* __restrict__ WeffT,
        const _Float16* __restrict__ w1T,
        const _Float16* __restrict__ w2T,
        const void* __restrict__ g1, const void* __restrict__ bb1,
        const void* __restrict__ w1, const void* __restrict__ fb1,
        const void* __restrict__ w2, const void* __restrict__ fb2,
        const void* __restrict__ g2, const void* __restrict__ bb2,
        void* __restrict__ out) {
    __shared__ Smem s;
    if (probe_is_f32(h))
        gat_body<true , TW>(s, h, adj, n_list, ssrc_h, sdst_h, WeffT, w1T, w2T,
                            g1, bb1, w1, fb1, w2, fb2, g2, bb2, out);
    else
        gat_body<false, TW>(s, h, adj, n_list, ssrc_h, sdst_h, WeffT, w1T, w2T,
                            g1, bb1, w1, fb1, w2, fb2, g2, bb2, out);
}

// ---------------------------------------------------------------------------
extern "C" void kernel_launch(void* const* d_in, const int* in_sizes, int n_in,
                              void* d_out, int out_size, void* d_ws, size_t ws_size,
                              hipStream_t stream) {
    (void)in_sizes; (void)n_in; (void)out_size;

    // ws layout (bytes):
    //   wsrc   [     0,   4096)  f32[1024]
    //   wdst   [  4096,   8192)  f32[1024]
    //   ssrc   [  8192, 139264)  f16[8192*8]
    //   sdst   [139264, 270336)  f16[8192*8]
    //   WeffT  [270336, 532480)  f16[128][1024]
    //   w1T    [532480, 598016)  f16[256][128]   (only if ws_size allows)
    //   w2T    [598016, 663552)  f16[128][256]   (only if ws_size allows)
    char* wsb = (char*)d_ws;
    float*     wsrc  = (float*)(wsb);
    float*     wdst  = (float*)(wsb + 4096);
    _Float16*  ssrc  = (_Float16*)(wsb + 8192);
    _Float16*  sdst  = (_Float16*)(wsb + 139264);
    _Float16*  WeffT = (_Float16*)(wsb + 270336);
    _Float16*  w1T   = (_Float16*)(wsb + 532480);
    _Float16*  w2T   = (_Float16*)(wsb + 598016);

    const bool big = ws_size >= 663552;

    k0s<<<8, 256, 0, stream>>>(d_in[3], d_in[4], d_in[5], d_in[0], wsrc, wdst);
    kB<<<big ? 1026 : 1024, 256, 0, stream>>>(
        d_in[3], d_in[6], d_in[0], wsrc, wdst, d_in[9], d_in[11],
        WeffT, ssrc, sdst, w1T, w2T);
    if (big)
        k_gat<true ><<<BN_ / NB, 512, 0, stream>>>(
            d_in[0], (const int*)d_in[1], (const int*)d_in[2], ssrc, sdst,
            WeffT, w1T, w2T,
            d_in[7], d_in[8], d_in[9], d_in[10], d_in[11], d_in[12],
            d_in[13], d_in[14], d_out);
    else
        k_gat<false><<<BN_ / NB, 512, 0, stream>>>(
            d_in[0], (const int*)d_in[1], (const int*)d_in[2], ssrc, sdst,
            WeffT, w1T, w2T,
            d_in[7], d_in[8], d_in[9], d_in[10], d_in[11], d_in[12],
            d_in[13], d_in[14], d_out);
}

// Round 9
// 165.993 us; speedup vs baseline: 1.0380x; 1.0380x over previous
//
#include <hip/hip_runtime.h>
#include <hip/hip_bf16.h>

// Problem constants
#define B_  16
#define N_  512
#define M_  16
#define H_  8
#define D_  128
#define BN_ 8192   // B_*N_
#define NB  16     // nodes per block in main kernel

typedef __attribute__((ext_vector_type(4))) float          f32x4;
typedef __attribute__((ext_vector_type(4))) _Float16       f16x4;
typedef __attribute__((ext_vector_type(8))) unsigned short u16x8;
typedef __attribute__((ext_vector_type(8))) _Float16       f16x8;

static __device__ __forceinline__ float bf2f(__hip_bfloat16 x) { return __bfloat162float(x); }
static __device__ __forceinline__ unsigned short f2bu(float x) {
    __hip_bfloat16 b = __float2bfloat16(x);
    return *reinterpret_cast<unsigned short*>(&b);
}
static __device__ __forceinline__ float bu2f(unsigned short u) {
    return __uint_as_float(((unsigned int)u) << 16);
}

// Load/store policy: interpret float tensors as f32 or bf16.
template <bool F32>
struct Pol {
    static __device__ __forceinline__ float ld(const void* p, int i) {
        if constexpr (F32) return ((const float*)p)[i];
        else               return bf2f(((const __hip_bfloat16*)p)[i]);
    }
    static __device__ __forceinline__ float4 ld4(const void* p, int i) {  // i%4==0
        if constexpr (F32) return *(const float4*)((const float*)p + i);
        else {
            const ushort4 u = *(const ushort4*)((const unsigned short*)p + i);
            return make_float4(bu2f(u.x), bu2f(u.y), bu2f(u.z), bu2f(u.w));
        }
    }
    static __device__ __forceinline__ void ld8(const void* p, long i, float* v) {  // i%8==0
        if constexpr (F32) {
            const float4 a = *(const float4*)((const float*)p + i);
            const float4 b = *(const float4*)((const float*)p + i + 4);
            v[0]=a.x; v[1]=a.y; v[2]=a.z; v[3]=a.w;
            v[4]=b.x; v[5]=b.y; v[6]=b.z; v[7]=b.w;
        } else {
            const u16x8 u = *(const u16x8*)((const unsigned short*)p + i);
            #pragma unroll
            for (int j = 0; j < 8; ++j) v[j] = bu2f(u[j]);
        }
    }
    static __device__ __forceinline__ void st8(void* p, long i, const float* v) {  // i%8==0
        if constexpr (F32) {
            *(float4*)((float*)p + i)     = make_float4(v[0], v[1], v[2], v[3]);
            *(float4*)((float*)p + i + 4) = make_float4(v[4], v[5], v[6], v[7]);
        } else {
            u16x8 u;
            #pragma unroll
            for (int j = 0; j < 8; ++j) u[j] = f2bu(v[j]);
            *(u16x8*)((unsigned short*)p + i) = u;
        }
    }
};

// Dtype probe (verbatim): f32 buffers read as bf16 at even index give
// random-exponent garbage; genuine bf16 stays small.
static __device__ __forceinline__ bool probe_is_f32(const void* h) {
    bool is_f32 = false;
    const __hip_bfloat16* hb = (const __hip_bfloat16*)h;
    for (int i = 0; i < 128; ++i) {
        const float v = bf2f(hb[2 * i]);
        if (!(fabsf(v) < 1e4f)) is_f32 = true;
    }
    return is_f32;
}

// ---------------------------------------------------------------------------
// K0 (prep, grid 522):
//   blk <  512 : WeffT[o][hd] = f16( sum_e W[hd][e] * Wo[(h*128+e)][o] )  [proven]
//   blk <  520 : wsrc/wdst[h][d] = sum_e W[h][d][e] * a_{src,dst}[h][e]   [proven]
//   blk == 520 : w1T[o][k] = f16(w1[k][o])   [256x128]  [proven round 8]
//   blk == 521 : w2T[o][k] = f16(w2[k][o])   [128x256]  [proven round 8]
// ---------------------------------------------------------------------------
template <bool F32>
static __device__ __forceinline__ void k0_body(
        const void* __restrict__ W,  const void* __restrict__ Wo,
        const void* __restrict__ a_src, const void* __restrict__ a_dst,
        const void* __restrict__ w1, const void* __restrict__ w2,
        float* __restrict__ wsrc, float* __restrict__ wdst,
        _Float16* __restrict__ WeffT, _Float16* __restrict__ w1T,
        _Float16* __restrict__ w2T, float* wrow /* shared [2*128] */) {
    using P = Pol<F32>;
    const int blk = blockIdx.x;
    const int t   = threadIdx.x;
    if (blk < 512) {
        const int half = t >> 7, o = t & 127;
        const int hd = blk * 2 + half;               // hd = h*128 + d
        wrow[half * 128 + o] = P::ld(W, hd * 128 + o);
        __syncthreads();
        const int hh = hd >> 7;
        float acc = 0.f;
        #pragma unroll 8
        for (int e = 0; e < 128; ++e)
            acc += wrow[half * 128 + e] * P::ld(Wo, (hh * 128 + e) * 128 + o);
        WeffT[(size_t)o * 1024 + hd] = (_Float16)acc;
    } else if (blk < 520) {
        const int hh = blk - 512;
        const int which = t >> 7, d = t & 127;
        const void* av = which ? a_dst : a_src;
        const int wbase = hh * (D_ * D_) + d * 128;
        float acc = 0.f;
        #pragma unroll 8
        for (int e = 0; e < 128; e += 4) {
            const float4 wv = P::ld4(W, wbase + e);
            const float4 aa = P::ld4(av, hh * 128 + e);
            acc += wv.x * aa.x + wv.y * aa.y + wv.z * aa.z + wv.w * aa.w;
        }
        (which ? wdst : wsrc)[hh * 128 + d] = acc;
    } else if (blk == 520) {
        const int o = t;                              // 0..255
        for (int k0 = 0; k0 < 128; k0 += 8) {
            f16x8 v;
            #pragma unroll
            for (int j = 0; j < 8; ++j) v[j] = (_Float16)P::ld(w1, (k0 + j) * 256 + o);
            *(f16x8*)(w1T + o * 128 + k0) = v;
        }
    } else {
        const int o = t & 127, kh = t >> 7;
        for (int k0 = kh * 128; k0 < kh * 128 + 128; k0 += 8) {
            f16x8 v;
            #pragma unroll
            for (int j = 0; j < 8; ++j) v[j] = (_Float16)P::ld(w2, (k0 + j) * 128 + o);
            *(f16x8*)(w2T + o * 256 + k0) = v;
        }
    }
}

__global__ __launch_bounds__(256) void k0(
        const void* W, const void* Wo, const void* a_src, const void* a_dst,
        const void* w1, const void* w2, const void* h,
        float* wsrc, float* wdst, _Float16* WeffT, _Float16* w1T, _Float16* w2T) {
    __shared__ float wrow[2 * 128];
    if (probe_is_f32(h)) k0_body<true >(W, Wo, a_src, a_dst, w1, w2, wsrc, wdst, WeffT, w1T, w2T, wrow);
    else                 k0_body<false>(W, Wo, a_src, a_dst, w1, w2, wsrc, wdst, WeffT, w1T, w2T, wrow);
}

// ---------------------------------------------------------------------------
// K1: scores.  [byte-identical to passing round 5]
// ---------------------------------------------------------------------------
template <bool F32>
static __device__ __forceinline__ void k1_body(
        const void* __restrict__ h, const float* __restrict__ wsrc,
        const float* __restrict__ wdst, _Float16* __restrict__ ssrc_h,
        _Float16* __restrict__ sdst_h, float* hls /*[16*132]*/, float* wls /*[16*132]*/) {
    using P = Pol<F32>;
    const int t   = threadIdx.x;
    const int bn0 = blockIdx.x * 16;
    {
        const int r = t >> 4, c0 = (t & 15) * 8;
        float v[8];
        P::ld8(h, (long)(bn0 + r) * 128 + c0, v);
        #pragma unroll
        for (int j = 0; j < 8; ++j) hls[r * 132 + c0 + j] = v[j];
        const int c = t >> 4;                         // c = which*8 + head
        const float* wp = (c >> 3) ? wdst : wsrc;
        const int woff = (c & 7) * 128 + c0;
        #pragma unroll
        for (int j = 0; j < 8; ++j) wls[c * 132 + c0 + j] = wp[woff + j];
    }
    __syncthreads();
    const int n = t >> 4, c = t & 15;
    float acc = 0.f;
    #pragma unroll
    for (int e = 0; e < 128; e += 4) {
        const float4 hv = *(const float4*)(hls + n * 132 + e);
        const float4 wv = *(const float4*)(wls + c * 132 + e);
        acc += hv.x * wv.x + hv.y * wv.y + hv.z * wv.z + hv.w * wv.w;
    }
    const int node = bn0 + n;
    if (c < 8) ssrc_h[node * 8 + c]       = (_Float16)acc;
    else       sdst_h[node * 8 + (c - 8)] = (_Float16)acc;
}

__global__ __launch_bounds__(256) void k1(const void* h, const float* wsrc,
                                          const float* wdst, _Float16* ssrc_h,
                                          _Float16* sdst_h) {
    __shared__ float hls[16 * 132];
    __shared__ float wls[16 * 132];
    if (probe_is_f32(h)) k1_body<true >(h, wsrc, wdst, ssrc_h, sdst_h, hls, wls);
    else                 k1_body<false>(h, wsrc, wdst, ssrc_h, sdst_h, hls, wls);
}

// ---------------------------------------------------------------------------
// Main fused kernel. 16 nodes/block, 512 threads (8 waves), grid 512.
// [round-5 structure — best measured 58.2 us — single change: FF1/FF2
//  B-fragments are INLINE f16x4 vector loads from pre-transposed w1T/w2T
//  (no register prefetch, so VGPR/occupancy match round 5).]
// MFMA layout (proven): A lane(lo,hi) reg j = A[lo][4*hi+j]; B = B[4*hi+j][lo];
// D reg q -> row 4*hi+q, col lo.
// ---------------------------------------------------------------------------
struct __align__(16) Smem {
    union {
        _Float16 Zh[NB][1024];                 // 32768   P4 -> G1 (f16, swizzled)
        struct {
            float    ts[NB][132];              // 8448    LN1 -> FF1/FF2 (padded)
            _Float16 us[NB][260];              // 8320    FF1 -> FF2 (padded)
            float    ys[NB][128];              // 8192    FF2 -> LN2
        } ff;
    } u;
    float hs[NB][128];                         // 8192    residual
    union {
        float attn[NB][16][8];                 // 8192    P2 -> P4
        float yln[NB][128];                    // 8192    G1 -> LN1
    } v;
    int   nls[NB][16];                         // 1024
    int   adjs[NB][16];                        // 1024
    float ssrc[NB][8];                         // 512
};

template <bool F32>
static __device__ __forceinline__ void gat_body(
        Smem& s,
        const void* __restrict__ h,
        const int*  __restrict__ adj,
        const int*  __restrict__ n_list,
        const _Float16* __restrict__ ssrc_h,
        const _Float16* __restrict__ sdst_h,
        const _Float16* __restrict__ WeffT,
        const _Float16* __restrict__ w1T,
        const _Float16* __restrict__ w2T,
        const void* __restrict__ g1, const void* __restrict__ bb1,
        const void* __restrict__ fb1, const void* __restrict__ fb2,
        const void* __restrict__ g2, const void* __restrict__ bb2,
        void* __restrict__ out) {
    using P = Pol<F32>;
    const int t   = threadIdx.x;
    const int bn0 = blockIdx.x * NB;
    const int b   = bn0 >> 9;                  // 512 nodes per batch
    const int l   = t & 63;
    const int w   = t >> 6;                    // wave 0..7
    const int lo  = l & 15;
    const int hi  = l >> 4;

    // ---- P1: self rows + neighbor lists + gathered ssrc  (512 threads)
    {
        const int r = t >> 5, c0 = (t & 31) * 4;
        const float4 v = P::ld4(h, (bn0 + r) * 128 + c0);
        *(float4*)&s.hs[r][c0] = v;
    }
    if (t < 256) {
        const int r = t >> 4, m = t & 15;
        s.nls[r][m]  = n_list[(bn0 + r) * M_ + m] & (N_ - 1);
        s.adjs[r][m] = adj[(bn0 + r) * M_ + m];
    }
    if (t < NB * 8) s.ssrc[t >> 3][t & 7] = (float)ssrc_h[bn0 * 8 + t];
    __syncthreads();

    // ---- P2: scores = mask(leaky(s_src + s_dst[nl]))   (256 threads)
    if (t < 256) {
        const int r = t >> 4, m = t & 15;
        const int nbr = s.nls[r][m];
        const f16x8 sd = *(const f16x8*)(sdst_h + (size_t)(b * N_ + nbr) * 8);
        const int amask = s.adjs[r][m];
        float sc[8];
        #pragma unroll
        for (int hh = 0; hh < 8; ++hh) {
            float x = s.ssrc[r][hh] + (float)sd[hh];
            x = x > 0.f ? x : 0.2f * x;        // leaky_relu BEFORE mask (ref order)
            if (amask == 0) x = -1e9f;
            sc[hh] = x;
        }
        *(float4*)&s.v.attn[r][m][0] = make_float4(sc[0], sc[1], sc[2], sc[3]);
        *(float4*)&s.v.attn[r][m][4] = make_float4(sc[4], sc[5], sc[6], sc[7]);
    }
    __syncthreads();

    // ---- P3: softmax over m   (128 threads)
    if (t < NB * 8) {
        const int r = t >> 3, hh = t & 7;
        float mx = -3.4e38f;
        #pragma unroll
        for (int m = 0; m < 16; ++m) mx = fmaxf(mx, s.v.attn[r][m][hh]);
        float ex[16], sum = 0.f;
        #pragma unroll
        for (int m = 0; m < 16; ++m) { ex[m] = __expf(s.v.attn[r][m][hh] - mx); sum += ex[m]; }
        const float inv = 1.f / sum;
        #pragma unroll
        for (int m = 0; m < 16; ++m) s.v.attn[r][m][hh] = ex[m] * inv;
    }
    __syncthreads();

    // ---- P4: Z[r][hh][d] = sum_m attn[r][m][hh] * h[nl[r][m]][d]
    //      512 threads: 32 threads/node, 4 d each.  (f16, swizzled)
    {
        const int r = t >> 5, dc = t & 31, d0 = dc * 4;
        float z[8][4];
        #pragma unroll
        for (int hh = 0; hh < 8; ++hh)
            #pragma unroll
            for (int jj = 0; jj < 4; ++jj) z[hh][jj] = 0.f;
        #pragma unroll 4
        for (int m = 0; m < 16; ++m) {
            const int nbr = s.nls[r][m];
            const float4 hv = P::ld4(h, (b * N_ + nbr) * 128 + d0);
            const float hv4[4] = { hv.x, hv.y, hv.z, hv.w };
            const float4 a0 = *(const float4*)&s.v.attn[r][m][0];
            const float4 a1 = *(const float4*)&s.v.attn[r][m][4];
            const float av[8] = { a0.x, a0.y, a0.z, a0.w, a1.x, a1.y, a1.z, a1.w };
            #pragma unroll
            for (int hh = 0; hh < 8; ++hh)
                #pragma unroll
                for (int jj = 0; jj < 4; ++jj) z[hh][jj] += av[hh] * hv4[jj];
        }
        char* zb = (char*)&s.u.Zh[0][0] + r * 2048;
        const int xo = (r & 7) << 4;
        #pragma unroll
        for (int hh = 0; hh < 8; ++hh) {
            f16x4 vv;
            #pragma unroll
            for (int jj = 0; jj < 4; ++jj) vv[jj] = (_Float16)z[hh][jj];
            *(f16x4*)(zb + ((hh * 256 + dc * 8) ^ xo)) = vv;
        }
    }
    __syncthreads();

    // ---- G1: yln = Zh @ WeffT^T + hs   (MFMA 16x16x16, K=1024; 8 waves x 16 cols)
    {
        const char* za  = (const char*)&s.u.Zh[0][0] + lo * 2048;
        const int   xo  = (lo & 7) << 4;
        const char* wb0 = (const char*)(WeffT + (size_t)(w * 16 + lo) * 1024);
        f32x4 acc0 = {0.f, 0.f, 0.f, 0.f};
        #pragma unroll 8
        for (int ks = 0; ks < 64; ++ks) {
            const int kb = ks * 32 + hi * 8;           // byte offset of k = ks*16 + hi*4
            const f16x4 a  = *(const f16x4*)(za + (kb ^ xo));
            const f16x4 b0 = *(const f16x4*)(wb0 + kb);
            acc0 = __builtin_amdgcn_mfma_f32_16x16x16f16(a, b0, acc0, 0, 0, 0);
        }
        const int o0 = w * 16 + lo;
        #pragma unroll
        for (int q = 0; q < 4; ++q) {
            const int rr = hi * 4 + q;
            s.v.yln[rr][o0] = acc0[q] + s.hs[rr][o0];
        }
    }
    __syncthreads();

    // ---- LN1 -> ts (f32, padded rows). 16 threads per row (256 threads).
    if (t < NB * 16) {
        const int r = t >> 4, j0 = (t & 15) * 8;
        const float4 x0 = *(const float4*)&s.v.yln[r][j0];
        const float4 x1 = *(const float4*)&s.v.yln[r][j0 + 4];
        const float x[8] = { x0.x, x0.y, x0.z, x0.w, x1.x, x1.y, x1.z, x1.w };
        float sm = 0.f, ss = 0.f;
        #pragma unroll
        for (int j = 0; j < 8; ++j) { sm += x[j]; ss += x[j] * x[j]; }
        #pragma unroll
        for (int off = 8; off > 0; off >>= 1) {
            sm += __shfl_xor(sm, off);
            ss += __shfl_xor(ss, off);
        }
        const float mu   = sm * (1.f / 128.f);
        const float var  = ss * (1.f / 128.f) - mu * mu;
        const float rstd = rsqrtf(var + 1e-5f);
        float gv[8], bv[8];
        P::ld8(g1, j0, gv);
        P::ld8(bb1, j0, bv);
        #pragma unroll
        for (int j = 0; j < 8; ++j)
            s.u.ff.ts[r][j0 + j] = (x[j] - mu) * rstd * gv[j] + bv[j];
    }
    __syncthreads();

    // ---- FF1: us = relu(ts @ w1 + b1)  (MFMA; 8 waves x 32 cols; K=128)
    //      B inline from w1T (f16x4 vector load, no prefetch).
    {
        f32x4 acc[2] = { {0.f,0.f,0.f,0.f}, {0.f,0.f,0.f,0.f} };
        #pragma unroll
        for (int ks = 0; ks < 8; ++ks) {
            const int k = ks * 16 + hi * 4;
            const float4 tv = *(const float4*)&s.u.ff.ts[lo][k];
            f16x4 a;
            a[0] = (_Float16)tv.x; a[1] = (_Float16)tv.y;
            a[2] = (_Float16)tv.z; a[3] = (_Float16)tv.w;
            #pragma unroll
            for (int nt = 0; nt < 2; ++nt) {
                const f16x4 bb = *(const f16x4*)(
                    w1T + (size_t)(w * 32 + nt * 16 + lo) * 128 + k);
                acc[nt] = __builtin_amdgcn_mfma_f32_16x16x16f16(a, bb, acc[nt], 0, 0, 0);
            }
        }
        #pragma unroll
        for (int nt = 0; nt < 2; ++nt) {
            const int o = w * 32 + nt * 16 + lo;
            const float bias = P::ld(fb1, o);
            #pragma unroll
            for (int q = 0; q < 4; ++q)
                s.u.ff.us[hi * 4 + q][o] = (_Float16)fmaxf(acc[nt][q] + bias, 0.f);
        }
    }
    __syncthreads();

    // ---- FF2: ys = us @ w2 + b2 + ts  (MFMA; 8 waves x 16 cols; K=256)
    //      B inline from w2T.
    {
        const int o0 = w * 16 + lo;
        f32x4 acc = {0.f, 0.f, 0.f, 0.f};
        #pragma unroll
        for (int ks = 0; ks < 16; ++ks) {
            const int k = ks * 16 + hi * 4;
            const f16x4 a  = *(const f16x4*)&s.u.ff.us[lo][k];
            const f16x4 bb = *(const f16x4*)(w2T + (size_t)o0 * 256 + k);
            acc = __builtin_amdgcn_mfma_f32_16x16x16f16(a, bb, acc, 0, 0, 0);
        }
        const float bias = P::ld(fb2, o0);
        #pragma unroll
        for (int q = 0; q < 4; ++q) {
            const int rr = hi * 4 + q;
            s.u.ff.ys[rr][o0] = acc[q] + bias + s.u.ff.ts[rr][o0];
        }
    }
    __syncthreads();

    // ---- LN2 -> out. 16 threads per row (256 threads).
    if (t < NB * 16) {
        const int r = t >> 4, j0 = (t & 15) * 8;
        const float4 x0 = *(const float4*)&s.u.ff.ys[r][j0];
        const float4 x1 = *(const float4*)&s.u.ff.ys[r][j0 + 4];
        const float x[8] = { x0.x, x0.y, x0.z, x0.w, x1.x, x1.y, x1.z, x1.w };
        float sm = 0.f, ss = 0.f;
        #pragma unroll
        for (int j = 0; j < 8; ++j) { sm += x[j]; ss += x[j] * x[j]; }
        #pragma unroll
        for (int off = 8; off > 0; off >>= 1) {
            sm += __shfl_xor(sm, off);
            ss += __shfl_xor(ss, off);
        }
        const float mu   = sm * (1.f / 128.f);
        const float var  = ss * (1.f / 128.f) - mu * mu;
        const float rstd = rsqrtf(var + 1e-5f);
        float gv[8], bv[8], o8[8];
        P::ld8(g2, j0, gv);
        P::ld8(bb2, j0, bv);
        #pragma unroll
        for (int j = 0; j < 8; ++j) o8[j] = (x[j] - mu) * rstd * gv[j] + bv[j];
        P::st8(out, (long)(bn0 + r) * 128 + j0, o8);
    }
}

__global__ __launch_bounds__(512) void k_gat(
        const void* __restrict__ h,
        const int*  __restrict__ adj,
        const int*  __restrict__ n_list,
        const _Float16* __restrict__ ssrc_h,
        const _Float16* __restrict__ sdst_h,
        const _Float16* __restrict__ WeffT,
        const _Float16* __restrict__ w1T,
        const _Float16* __restrict__ w2T,
        const void* __restrict__ g1, const void* __restrict__ bb1,
        const void* __restrict__ fb1, const void* __restrict__ fb2,
        const void* __restrict__ g2, const void* __restrict__ bb2,
        void* __restrict__ out) {
    __shared__ Smem s;
    if (probe_is_f32(h))
        gat_body<true >(s, h, adj, n_list, ssrc_h, sdst_h, WeffT, w1T, w2T,
                        g1, bb1, fb1, fb2, g2, bb2, out);
    else
        gat_body<false>(s, h, adj, n_list, ssrc_h, sdst_h, WeffT, w1T, w2T,
                        g1, bb1, fb1, fb2, g2, bb2, out);
}

// ---------------------------------------------------------------------------
extern "C" void kernel_launch(void* const* d_in, const int* in_sizes, int n_in,
                              void* d_out, int out_size, void* d_ws, size_t ws_size,
                              hipStream_t stream) {
    (void)in_sizes; (void)n_in; (void)out_size; (void)ws_size;

    // ws layout (bytes) — total 663552 (round 8 proved ws_size >= 663552):
    //   wsrc   [     0,   4096)  f32[1024]
    //   wdst   [  4096,   8192)  f32[1024]
    //   ssrc   [  8192, 139264)  f16[8192*8]
    //   sdst   [139264, 270336)  f16[8192*8]
    //   WeffT  [270336, 532480)  f16[128][1024]
    //   w1T    [532480, 598016)  f16[256][128]
    //   w2T    [598016, 663552)  f16[128][256]
    char* wsb = (char*)d_ws;
    float*     wsrc  = (float*)(wsb);
    float*     wdst  = (float*)(wsb + 4096);
    _Float16*  ssrc  = (_Float16*)(wsb + 8192);
    _Float16*  sdst  = (_Float16*)(wsb + 139264);
    _Float16*  WeffT = (_Float16*)(wsb + 270336);
    _Float16*  w1T   = (_Float16*)(wsb + 532480);
    _Float16*  w2T   = (_Float16*)(wsb + 598016);

    k0<<<522,      256, 0, stream>>>(d_in[3], d_in[6], d_in[4], d_in[5],
                                     d_in[9], d_in[11], d_in[0],
                                     wsrc, wdst, WeffT, w1T, w2T);
    k1<<<BN_ / 16, 256, 0, stream>>>(d_in[0], wsrc, wdst, ssrc, sdst);
    k_gat<<<BN_ / NB, 512, 0, stream>>>(
        d_in[0], (const int*)d_in[1], (const int*)d_in[2], ssrc, sdst,
        WeffT, w1T, w2T,
        d_in[7], d_in[8], d_in[10], d_in[12], d_in[13], d_in[14], d_out);
}

// Round 11
// 161.492 us; speedup vs baseline: 1.0670x; 1.0279x over previous
//
#include <hip/hip_runtime.h>
#include <hip/hip_bf16.h>

// Problem constants
#define B_  16
#define N_  512
#define M_  16
#define H_  8
#define D_  128
#define BN_ 8192   // B_*N_
#define NB  16     // nodes per block in main kernel

typedef __attribute__((ext_vector_type(4))) float          f32x4;
typedef __attribute__((ext_vector_type(4))) _Float16       f16x4;
typedef __attribute__((ext_vector_type(8))) unsigned short u16x8;
typedef __attribute__((ext_vector_type(8))) _Float16       f16x8;

static __device__ __forceinline__ float bf2f(__hip_bfloat16 x) { return __bfloat162float(x); }
static __device__ __forceinline__ unsigned short f2bu(float x) {
    __hip_bfloat16 b = __float2bfloat16(x);
    return *reinterpret_cast<unsigned short*>(&b);
}
static __device__ __forceinline__ float bu2f(unsigned short u) {
    return __uint_as_float(((unsigned int)u) << 16);
}

// Load/store policy: interpret float tensors as f32 or bf16.
template <bool F32>
struct Pol {
    static __device__ __forceinline__ float ld(const void* p, int i) {
        if constexpr (F32) return ((const float*)p)[i];
        else               return bf2f(((const __hip_bfloat16*)p)[i]);
    }
    static __device__ __forceinline__ float4 ld4(const void* p, int i) {  // i%4==0
        if constexpr (F32) return *(const float4*)((const float*)p + i);
        else {
            const ushort4 u = *(const ushort4*)((const unsigned short*)p + i);
            return make_float4(bu2f(u.x), bu2f(u.y), bu2f(u.z), bu2f(u.w));
        }
    }
    static __device__ __forceinline__ void ld8(const void* p, long i, float* v) {  // i%8==0
        if constexpr (F32) {
            const float4 a = *(const float4*)((const float*)p + i);
            const float4 b = *(const float4*)((const float*)p + i + 4);
            v[0]=a.x; v[1]=a.y; v[2]=a.z; v[3]=a.w;
            v[4]=b.x; v[5]=b.y; v[6]=b.z; v[7]=b.w;
        } else {
            const u16x8 u = *(const u16x8*)((const unsigned short*)p + i);
            #pragma unroll
            for (int j = 0; j < 8; ++j) v[j] = bu2f(u[j]);
        }
    }
    static __device__ __forceinline__ void st8(void* p, long i, const float* v) {  // i%8==0
        if constexpr (F32) {
            *(float4*)((float*)p + i)     = make_float4(v[0], v[1], v[2], v[3]);
            *(float4*)((float*)p + i + 4) = make_float4(v[4], v[5], v[6], v[7]);
        } else {
            u16x8 u;
            #pragma unroll
            for (int j = 0; j < 8; ++j) u[j] = f2bu(v[j]);
            *(u16x8*)((unsigned short*)p + i) = u;
        }
    }
};

// Dtype probe (verbatim): f32 buffers read as bf16 at even index give
// random-exponent garbage; genuine bf16 stays small.
static __device__ __forceinline__ bool probe_is_f32(const void* h) {
    bool is_f32 = false;
    const __hip_bfloat16* hb = (const __hip_bfloat16*)h;
    for (int i = 0; i < 128; ++i) {
        const float v = bf2f(hb[2 * i]);
        if (!(fabsf(v) < 1e4f)) is_f32 = true;
    }
    return is_f32;
}

// ---------------------------------------------------------------------------
// K0 (prep, grid 520):  [byte-identical to passing round 5]
//   blk <  512 : WeffT[o][hd] = f16( sum_e W[hd][e] * Wo[(h*128+e)][o] )
//   blk >= 512 : wsrc/wdst[h][d] = sum_e W[h][d][e] * a_{src,dst}[h][e]  (f32)
// ---------------------------------------------------------------------------
template <bool F32>
static __device__ __forceinline__ void k0_body(
        const void* __restrict__ W,  const void* __restrict__ Wo,
        const void* __restrict__ a_src, const void* __restrict__ a_dst,
        float* __restrict__ wsrc, float* __restrict__ wdst,
        _Float16* __restrict__ WeffT, float* wrow /* shared [2*128] */) {
    using P = Pol<F32>;
    const int blk = blockIdx.x;
    const int t   = threadIdx.x;
    if (blk < 512) {
        const int half = t >> 7, o = t & 127;
        const int hd = blk * 2 + half;               // hd = h*128 + d
        wrow[half * 128 + o] = P::ld(W, hd * 128 + o);
        __syncthreads();
        const int hh = hd >> 7;
        float acc = 0.f;
        #pragma unroll 8
        for (int e = 0; e < 128; ++e)
            acc += wrow[half * 128 + e] * P::ld(Wo, (hh * 128 + e) * 128 + o);
        WeffT[(size_t)o * 1024 + hd] = (_Float16)acc;
    } else {
        const int hh = blk - 512;
        const int which = t >> 7, d = t & 127;
        const void* av = which ? a_dst : a_src;
        const int wbase = hh * (D_ * D_) + d * 128;
        float acc = 0.f;
        #pragma unroll 8
        for (int e = 0; e < 128; e += 4) {
            const float4 wv = P::ld4(W, wbase + e);
            const float4 aa = P::ld4(av, hh * 128 + e);
            acc += wv.x * aa.x + wv.y * aa.y + wv.z * aa.z + wv.w * aa.w;
        }
        (which ? wdst : wsrc)[hh * 128 + d] = acc;
    }
}

__global__ __launch_bounds__(256) void k0(
        const void* W, const void* Wo, const void* a_src, const void* a_dst,
        const void* h, float* wsrc, float* wdst, _Float16* WeffT) {
    __shared__ float wrow[2 * 128];
    if (probe_is_f32(h)) k0_body<true >(W, Wo, a_src, a_dst, wsrc, wdst, WeffT, wrow);
    else                 k0_body<false>(W, Wo, a_src, a_dst, wsrc, wdst, WeffT, wrow);
}

// ---------------------------------------------------------------------------
// Main fused kernel. 16 nodes/block, 512 threads (8 waves), grid 512.
// Round-5 structure (58.2 us proven) + INTEGRATED score computation:
//   P2 computes both s_src (own row) and s_dst (neighbor row, streamed from
//   global) dots on the fly — 2 threads per (r,m) pair, shfl_xor(1) reduce.
//   This deletes the separate k1 launch and the f16 score round-trip.
// wsrc/wdst staged in 8 KB LDS aliased over the Zh union (free until P4).
// MFMA layout (proven): A lane(lo,hi) reg j = A[lo][4*hi+j]; B = B[4*hi+j][lo];
// D reg q -> row 4*hi+q, col lo.
// ---------------------------------------------------------------------------
struct __align__(16) Smem {
    union {
        _Float16 Zh[NB][1024];                 // 32768   P4 -> G1 (f16, swizzled)
        float    wsd[2][1024];                 // 8192    P1 -> P2 (wsrc, wdst)
        struct {
            float    ts[NB][132];              // 8448    LN1 -> FF1/FF2 (padded)
            _Float16 us[NB][260];              // 8320    FF1 -> FF2 (padded)
            float    ys[NB][128];              // 8192    FF2 -> LN2
        } ff;
    } u;
    float hs[NB][128];                         // 8192    residual + src-dot input
    union {
        float attn[NB][16][8];                 // 8192    P2 -> P4
        float yln[NB][128];                    // 8192    G1 -> LN1
    } v;
    int   nls[NB][16];                         // 1024
    int   adjs[NB][16];                        // 1024
};

template <bool F32>
static __device__ __forceinline__ void gat_body(
        Smem& s,
        const void* __restrict__ h,
        const int*  __restrict__ adj,
        const int*  __restrict__ n_list,
        const float* __restrict__ wsrc,
        const float* __restrict__ wdst,
        const _Float16* __restrict__ WeffT,
        const void* __restrict__ g1, const void* __restrict__ bb1,
        const void* __restrict__ w1, const void* __restrict__ fb1,
        const void* __restrict__ w2, const void* __restrict__ fb2,
        const void* __restrict__ g2, const void* __restrict__ bb2,
        void* __restrict__ out) {
    using P = Pol<F32>;
    const int t   = threadIdx.x;
    const int bn0 = blockIdx.x * NB;
    const int b   = bn0 >> 9;                  // 512 nodes per batch
    const int l   = t & 63;
    const int w   = t >> 6;                    // wave 0..7
    const int lo  = l & 15;
    const int hi  = l >> 4;

    // ---- P1: self rows + neighbor lists + wsrc/wdst staging (512 threads)
    {
        const int r = t >> 5, c0 = (t & 31) * 4;
        const float4 v = P::ld4(h, (bn0 + r) * 128 + c0);
        *(float4*)&s.hs[r][c0] = v;
    }
    if (t < 256) {
        const int r = t >> 4, m = t & 15;
        s.nls[r][m]  = n_list[(bn0 + r) * M_ + m] & (N_ - 1);
        s.adjs[r][m] = adj[(bn0 + r) * M_ + m];
        *(float4*)&s.u.wsd[0][t * 4] = *(const float4*)(wsrc + t * 4);
    } else {
        const int i = t - 256;
        *(float4*)&s.u.wsd[1][i * 4] = *(const float4*)(wdst + i * 4);
    }
    __syncthreads();

    // ---- P2: scores = mask(leaky(s_src + s_dst[nl])), dots computed in-block.
    //      2 threads per (r,m) pair; each handles 64 elems of both dots.
    {
        const int p = t >> 1, sub = t & 1;
        const int r = p >> 4, m = p & 15;
        const int nbr  = s.nls[r][m];
        const int gbase = (b * N_ + nbr) * 128 + sub * 64;
        const int lbase = sub * 64;
        float accS[8], accD[8];
        #pragma unroll
        for (int hh = 0; hh < 8; ++hh) { accS[hh] = 0.f; accD[hh] = 0.f; }
        #pragma unroll 4
        for (int c = 0; c < 64; c += 4) {
            const float4 hv = P::ld4(h, gbase + c);              // neighbor row
            const float4 sv = *(const float4*)&s.hs[r][lbase + c]; // own row
            #pragma unroll
            for (int hh = 0; hh < 8; ++hh) {
                const float4 wdv = *(const float4*)&s.u.wsd[1][hh * 128 + lbase + c];
                const float4 wsv = *(const float4*)&s.u.wsd[0][hh * 128 + lbase + c];
                accD[hh] += hv.x * wdv.x + hv.y * wdv.y + hv.z * wdv.z + hv.w * wdv.w;
                accS[hh] += sv.x * wsv.x + sv.y * wsv.y + sv.z * wsv.z + sv.w * wsv.w;
            }
        }
        #pragma unroll
        for (int hh = 0; hh < 8; ++hh) {
            accS[hh] += __shfl_xor(accS[hh], 1);
            accD[hh] += __shfl_xor(accD[hh], 1);
        }
        if (sub == 0) {
            const int amask = s.adjs[r][m];
            float sc[8];
            #pragma unroll
            for (int hh = 0; hh < 8; ++hh) {
                float x = accS[hh] + accD[hh];
                x = x > 0.f ? x : 0.2f * x;    // leaky_relu BEFORE mask (ref order)
                if (amask == 0) x = -1e9f;
                sc[hh] = x;
            }
            *(float4*)&s.v.attn[r][m][0] = make_float4(sc[0], sc[1], sc[2], sc[3]);
            *(float4*)&s.v.attn[r][m][4] = make_float4(sc[4], sc[5], sc[6], sc[7]);
        }
    }
    __syncthreads();

    // ---- P3: softmax over m   (128 threads)
    if (t < NB * 8) {
        const int r = t >> 3, hh = t & 7;
        float mx = -3.4e38f;
        #pragma unroll
        for (int m = 0; m < 16; ++m) mx = fmaxf(mx, s.v.attn[r][m][hh]);
        float ex[16], sum = 0.f;
        #pragma unroll
        for (int m = 0; m < 16; ++m) { ex[m] = __expf(s.v.attn[r][m][hh] - mx); sum += ex[m]; }
        const float inv = 1.f / sum;
        #pragma unroll
        for (int m = 0; m < 16; ++m) s.v.attn[r][m][hh] = ex[m] * inv;
    }
    __syncthreads();

    // ---- P4: Z[r][hh][d] = sum_m attn[r][m][hh] * h[nl[r][m]][d]
    //      512 threads: 32 threads/node, 4 d each.  (f16, swizzled)
    {
        const int r = t >> 5, dc = t & 31, d0 = dc * 4;
        float z[8][4];
        #pragma unroll
        for (int hh = 0; hh < 8; ++hh)
            #pragma unroll
            for (int jj = 0; jj < 4; ++jj) z[hh][jj] = 0.f;
        #pragma unroll 4
        for (int m = 0; m < 16; ++m) {
            const int nbr = s.nls[r][m];
            const float4 hv = P::ld4(h, (b * N_ + nbr) * 128 + d0);
            const float hv4[4] = { hv.x, hv.y, hv.z, hv.w };
            const float4 a0 = *(const float4*)&s.v.attn[r][m][0];
            const float4 a1 = *(const float4*)&s.v.attn[r][m][4];
            const float av[8] = { a0.x, a0.y, a0.z, a0.w, a1.x, a1.y, a1.z, a1.w };
            #pragma unroll
            for (int hh = 0; hh < 8; ++hh)
                #pragma unroll
                for (int jj = 0; jj < 4; ++jj) z[hh][jj] += av[hh] * hv4[jj];
        }
        char* zb = (char*)&s.u.Zh[0][0] + r * 2048;
        const int xo = (r & 7) << 4;
        #pragma unroll
        for (int hh = 0; hh < 8; ++hh) {
            f16x4 vv;
            #pragma unroll
            for (int jj = 0; jj < 4; ++jj) vv[jj] = (_Float16)z[hh][jj];
            *(f16x4*)(zb + ((hh * 256 + dc * 8) ^ xo)) = vv;
        }
    }
    __syncthreads();

    // ---- G1: yln = Zh @ WeffT^T + hs   (MFMA 16x16x16, K=1024; 8 waves x 16 cols)
    {
        const char* za  = (const char*)&s.u.Zh[0][0] + lo * 2048;
        const int   xo  = (lo & 7) << 4;
        const char* wb0 = (const char*)(WeffT + (size_t)(w * 16 + lo) * 1024);
        f32x4 acc0 = {0.f, 0.f, 0.f, 0.f};
        #pragma unroll 8
        for (int ks = 0; ks < 64; ++ks) {
            const int kb = ks * 32 + hi * 8;           // byte offset of k = ks*16 + hi*4
            const f16x4 a  = *(const f16x4*)(za + (kb ^ xo));
            const f16x4 b0 = *(const f16x4*)(wb0 + kb);
            acc0 = __builtin_amdgcn_mfma_f32_16x16x16f16(a, b0, acc0, 0, 0, 0);
        }
        const int o0 = w * 16 + lo;
        #pragma unroll
        for (int q = 0; q < 4; ++q) {
            const int rr = hi * 4 + q;
            s.v.yln[rr][o0] = acc0[q] + s.hs[rr][o0];
        }
    }
    __syncthreads();

    // ---- LN1 -> ts (f32, padded rows). 16 threads per row (256 threads).
    if (t < NB * 16) {
        const int r = t >> 4, j0 = (t & 15) * 8;
        const float4 x0 = *(const float4*)&s.v.yln[r][j0];
        const float4 x1 = *(const float4*)&s.v.yln[r][j0 + 4];
        const float x[8] = { x0.x, x0.y, x0.z, x0.w, x1.x, x1.y, x1.z, x1.w };
        float sm = 0.f, ss = 0.f;
        #pragma unroll
        for (int j = 0; j < 8; ++j) { sm += x[j]; ss += x[j] * x[j]; }
        #pragma unroll
        for (int off = 8; off > 0; off >>= 1) {
            sm += __shfl_xor(sm, off);
            ss += __shfl_xor(ss, off);
        }
        const float mu   = sm * (1.f / 128.f);
        const float var  = ss * (1.f / 128.f) - mu * mu;
        const float rstd = rsqrtf(var + 1e-5f);
        float gv[8], bv[8];
        P::ld8(g1, j0, gv);
        P::ld8(bb1, j0, bv);
        #pragma unroll
        for (int j = 0; j < 8; ++j)
            s.u.ff.ts[r][j0 + j] = (x[j] - mu) * rstd * gv[j] + bv[j];
    }
    __syncthreads();

    // ---- FF1: us = relu(ts @ w1 + b1)  (MFMA; 8 waves x 32 cols; K=128)
    {
        f32x4 acc[2] = { {0.f,0.f,0.f,0.f}, {0.f,0.f,0.f,0.f} };
        #pragma unroll
        for (int ks = 0; ks < 8; ++ks) {
            const int k = ks * 16 + hi * 4;
            const float4 tv = *(const float4*)&s.u.ff.ts[lo][k];
            f16x4 a;
            a[0] = (_Float16)tv.x; a[1] = (_Float16)tv.y;
            a[2] = (_Float16)tv.z; a[3] = (_Float16)tv.w;
            #pragma unroll
            for (int nt = 0; nt < 2; ++nt) {
                const int o = w * 32 + nt * 16 + lo;
                f16x4 bb;
                #pragma unroll
                for (int j = 0; j < 4; ++j) bb[j] = (_Float16)P::ld(w1, (k + j) * 256 + o);
                acc[nt] = __builtin_amdgcn_mfma_f32_16x16x16f16(a, bb, acc[nt], 0, 0, 0);
            }
        }
        #pragma unroll
        for (int nt = 0; nt < 2; ++nt) {
            const int o = w * 32 + nt * 16 + lo;
            const float bias = P::ld(fb1, o);
            #pragma unroll
            for (int q = 0; q < 4; ++q)
                s.u.ff.us[hi * 4 + q][o] = (_Float16)fmaxf(acc[nt][q] + bias, 0.f);
        }
    }
    __syncthreads();

    // ---- FF2: ys = us @ w2 + b2 + ts  (MFMA; 8 waves x 16 cols; K=256)
    {
        const int o0 = w * 16 + lo;
        f32x4 acc = {0.f, 0.f, 0.f, 0.f};
        #pragma unroll
        for (int ks = 0; ks < 16; ++ks) {
            const int k = ks * 16 + hi * 4;
            const f16x4 a = *(const f16x4*)&s.u.ff.us[lo][k];
            f16x4 bb;
            #pragma unroll
            for (int j = 0; j < 4; ++j) bb[j] = (_Float16)P::ld(w2, (k + j) * 128 + o0);
            acc = __builtin_amdgcn_mfma_f32_16x16x16f16(a, bb, acc, 0, 0, 0);
        }
        const float bias = P::ld(fb2, o0);
        #pragma unroll
        for (int q = 0; q < 4; ++q) {
            const int rr = hi * 4 + q;
            s.u.ff.ys[rr][o0] = acc[q] + bias + s.u.ff.ts[rr][o0];
        }
    }
    __syncthreads();

    // ---- LN2 -> out. 16 threads per row (256 threads).
    if (t < NB * 16) {
        const int r = t >> 4, j0 = (t & 15) * 8;
        const float4 x0 = *(const float4*)&s.u.ff.ys[r][j0];
        const float4 x1 = *(const float4*)&s.u.ff.ys[r][j0 + 4];
        const float x[8] = { x0.x, x0.y, x0.z, x0.w, x1.x, x1.y, x1.z, x1.w };
        float sm = 0.f, ss = 0.f;
        #pragma unroll
        for (int j = 0; j < 8; ++j) { sm += x[j]; ss += x[j] * x[j]; }
        #pragma unroll
        for (int off = 8; off > 0; off >>= 1) {
            sm += __shfl_xor(sm, off);
            ss += __shfl_xor(ss, off);
        }
        const float mu   = sm * (1.f / 128.f);
        const float var  = ss * (1.f / 128.f) - mu * mu;
        const float rstd = rsqrtf(var + 1e-5f);
        float gv[8], bv[8], o8[8];
        P::ld8(g2, j0, gv);
        P::ld8(bb2, j0, bv);
        #pragma unroll
        for (int j = 0; j < 8; ++j) o8[j] = (x[j] - mu) * rstd * gv[j] + bv[j];
        P::st8(out, (long)(bn0 + r) * 128 + j0, o8);
    }
}

__global__ __launch_bounds__(512) void k_gat(
        const void* __restrict__ h,
        const int*  __restrict__ adj,
        const int*  __restrict__ n_list,
        const float* __restrict__ wsrc,
        const float* __restrict__ wdst,
        const _Float16* __restrict__ WeffT,
        const void* __restrict__ g1, const void* __restrict__ bb1,
        const void* __restrict__ w1, const void* __restrict__ fb1,
        const void* __restrict__ w2, const void* __restrict__ fb2,
        const void* __restrict__ g2, const void* __restrict__ bb2,
        void* __restrict__ out) {
    __shared__ Smem s;
    if (probe_is_f32(h))
        gat_body<true >(s, h, adj, n_list, wsrc, wdst, WeffT,
                        g1, bb1, w1, fb1, w2, fb2, g2, bb2, out);
    else
        gat_body<false>(s, h, adj, n_list, wsrc, wdst, WeffT,
                        g1, bb1, w1, fb1, w2, fb2, g2, bb2, out);
}

// ---------------------------------------------------------------------------
extern "C" void kernel_launch(void* const* d_in, const int* in_sizes, int n_in,
                              void* d_out, int out_size, void* d_ws, size_t ws_size,
                              hipStream_t stream) {
    (void)in_sizes; (void)n_in; (void)out_size; (void)ws_size;

    // ws layout (bytes):
    //   wsrc   [     0,   4096)  f32[1024]
    //   wdst   [  4096,   8192)  f32[1024]
    //   WeffT  [  8192, 270336)  f16[128][1024]
    char* wsb = (char*)d_ws;
    float*     wsrc  = (float*)(wsb);
    float*     wdst  = (float*)(wsb + 4096);
    _Float16*  WeffT = (_Float16*)(wsb + 8192);

    k0<<<520, 256, 0, stream>>>(d_in[3], d_in[6], d_in[4], d_in[5], d_in[0],
                                wsrc, wdst, WeffT);
    k_gat<<<BN_ / NB, 512, 0, stream>>>(
        d_in[0], (const int*)d_in[1], (const int*)d_in[2], wsrc, wdst, WeffT,
        d_in[7], d_in[8], d_in[9], d_in[10], d_in[11], d_in[12],
        d_in[13], d_in[14], d_out);
}

// Round 12
// 158.824 us; speedup vs baseline: 1.0849x; 1.0168x over previous
//
#include <hip/hip_runtime.h>
#include <hip/hip_bf16.h>

// Problem constants
#define B_  16
#define N_  512
#define M_  16
#define H_  8
#define D_  128
#define BN_ 8192   // B_*N_
#define NB  16     // nodes per block in main kernel

typedef __attribute__((ext_vector_type(4))) float          f32x4;
typedef __attribute__((ext_vector_type(4))) _Float16       f16x4;
typedef __attribute__((ext_vector_type(8))) unsigned short u16x8;
typedef __attribute__((ext_vector_type(8))) _Float16       f16x8;

static __device__ __forceinline__ float bf2f(__hip_bfloat16 x) { return __bfloat162float(x); }
static __device__ __forceinline__ unsigned short f2bu(float x) {
    __hip_bfloat16 b = __float2bfloat16(x);
    return *reinterpret_cast<unsigned short*>(&b);
}
static __device__ __forceinline__ float bu2f(unsigned short u) {
    return __uint_as_float(((unsigned int)u) << 16);
}

// Load/store policy: interpret float tensors as f32 or bf16.
template <bool F32>
struct Pol {
    static __device__ __forceinline__ float ld(const void* p, int i) {
        if constexpr (F32) return ((const float*)p)[i];
        else               return bf2f(((const __hip_bfloat16*)p)[i]);
    }
    static __device__ __forceinline__ float4 ld4(const void* p, int i) {  // i%4==0
        if constexpr (F32) return *(const float4*)((const float*)p + i);
        else {
            const ushort4 u = *(const ushort4*)((const unsigned short*)p + i);
            return make_float4(bu2f(u.x), bu2f(u.y), bu2f(u.z), bu2f(u.w));
        }
    }
    static __device__ __forceinline__ void ld8(const void* p, long i, float* v) {  // i%8==0
        if constexpr (F32) {
            const float4 a = *(const float4*)((const float*)p + i);
            const float4 b = *(const float4*)((const float*)p + i + 4);
            v[0]=a.x; v[1]=a.y; v[2]=a.z; v[3]=a.w;
            v[4]=b.x; v[5]=b.y; v[6]=b.z; v[7]=b.w;
        } else {
            const u16x8 u = *(const u16x8*)((const unsigned short*)p + i);
            #pragma unroll
            for (int j = 0; j < 8; ++j) v[j] = bu2f(u[j]);
        }
    }
    static __device__ __forceinline__ void st8(void* p, long i, const float* v) {  // i%8==0
        if constexpr (F32) {
            *(float4*)((float*)p + i)     = make_float4(v[0], v[1], v[2], v[3]);
            *(float4*)((float*)p + i + 4) = make_float4(v[4], v[5], v[6], v[7]);
        } else {
            u16x8 u;
            #pragma unroll
            for (int j = 0; j < 8; ++j) u[j] = f2bu(v[j]);
            *(u16x8*)((unsigned short*)p + i) = u;
        }
    }
};

// Dtype probe (verbatim): f32 buffers read as bf16 at even index give
// random-exponent garbage; genuine bf16 stays small.
static __device__ __forceinline__ bool probe_is_f32(const void* h) {
    bool is_f32 = false;
    const __hip_bfloat16* hb = (const __hip_bfloat16*)h;
    for (int i = 0; i < 128; ++i) {
        const float v = bf2f(hb[2 * i]);
        if (!(fabsf(v) < 1e4f)) is_f32 = true;
    }
    return is_f32;
}

// ---------------------------------------------------------------------------
// K0 (prep, grid 520):  [byte-identical to passing rounds 5/11]
//   blk <  512 : WeffT[o][hd] = f16( sum_e W[hd][e] * Wo[(h*128+e)][o] )
//   blk >= 512 : wsrc/wdst[h][d] = sum_e W[h][d][e] * a_{src,dst}[h][e]  (f32)
// ---------------------------------------------------------------------------
template <bool F32>
static __device__ __forceinline__ void k0_body(
        const void* __restrict__ W,  const void* __restrict__ Wo,
        const void* __restrict__ a_src, const void* __restrict__ a_dst,
        float* __restrict__ wsrc, float* __restrict__ wdst,
        _Float16* __restrict__ WeffT, float* wrow /* shared [2*128] */) {
    using P = Pol<F32>;
    const int blk = blockIdx.x;
    const int t   = threadIdx.x;
    if (blk < 512) {
        const int half = t >> 7, o = t & 127;
        const int hd = blk * 2 + half;               // hd = h*128 + d
        wrow[half * 128 + o] = P::ld(W, hd * 128 + o);
        __syncthreads();
        const int hh = hd >> 7;
        float acc = 0.f;
        #pragma unroll 8
        for (int e = 0; e < 128; ++e)
            acc += wrow[half * 128 + e] * P::ld(Wo, (hh * 128 + e) * 128 + o);
        WeffT[(size_t)o * 1024 + hd] = (_Float16)acc;
    } else {
        const int hh = blk - 512;
        const int which = t >> 7, d = t & 127;
        const void* av = which ? a_dst : a_src;
        const int wbase = hh * (D_ * D_) + d * 128;
        float acc = 0.f;
        #pragma unroll 8
        for (int e = 0; e < 128; e += 4) {
            const float4 wv = P::ld4(W, wbase + e);
            const float4 aa = P::ld4(av, hh * 128 + e);
            acc += wv.x * aa.x + wv.y * aa.y + wv.z * aa.z + wv.w * aa.w;
        }
        (which ? wdst : wsrc)[hh * 128 + d] = acc;
    }
}

__global__ __launch_bounds__(256) void k0(
        const void* W, const void* Wo, const void* a_src, const void* a_dst,
        const void* h, float* wsrc, float* wdst, _Float16* WeffT) {
    __shared__ float wrow[2 * 128];
    if (probe_is_f32(h)) k0_body<true >(W, Wo, a_src, a_dst, wsrc, wdst, WeffT, wrow);
    else                 k0_body<false>(W, Wo, a_src, a_dst, wsrc, wdst, WeffT, wrow);
}

// ---------------------------------------------------------------------------
// Main fused kernel. 16 nodes/block, 512 threads (8 waves), grid 512.
// Round-11 structure (passed, f32 scores in-block) with P2 de-duplicated:
//   - s_src computed ONCE per (node, head): 256 tiny 64-MAC tasks, t<256,
//     stored to s.ssrc (512 B), one extra barrier.
//   - all 512 threads do only the dst dots (512 FMA/thread, was 1024).
// wsrc/wdst staged in 8 KB LDS aliased over the Zh union (free until P4).
// MFMA layout (proven): A lane(lo,hi) reg j = A[lo][4*hi+j]; B = B[4*hi+j][lo];
// D reg q -> row 4*hi+q, col lo.
// ---------------------------------------------------------------------------
struct __align__(16) Smem {
    union {
        _Float16 Zh[NB][1024];                 // 32768   P4 -> G1 (f16, swizzled)
        float    wsd[2][1024];                 // 8192    P1 -> P2 (wsrc, wdst)
        struct {
            float    ts[NB][132];              // 8448    LN1 -> FF1/FF2 (padded)
            _Float16 us[NB][260];              // 8320    FF1 -> FF2 (padded)
            float    ys[NB][128];              // 8192    FF2 -> LN2
        } ff;
    } u;
    float hs[NB][128];                         // 8192    residual + src-dot input
    union {
        float attn[NB][16][8];                 // 8192    P2 -> P4
        float yln[NB][128];                    // 8192    G1 -> LN1
    } v;
    int   nls[NB][16];                         // 1024
    int   adjs[NB][16];                        // 1024
    float ssrc[NB][8];                         // 512     P2a -> P2b
};

template <bool F32>
static __device__ __forceinline__ void gat_body(
        Smem& s,
        const void* __restrict__ h,
        const int*  __restrict__ adj,
        const int*  __restrict__ n_list,
        const float* __restrict__ wsrc,
        const float* __restrict__ wdst,
        const _Float16* __restrict__ WeffT,
        const void* __restrict__ g1, const void* __restrict__ bb1,
        const void* __restrict__ w1, const void* __restrict__ fb1,
        const void* __restrict__ w2, const void* __restrict__ fb2,
        const void* __restrict__ g2, const void* __restrict__ bb2,
        void* __restrict__ out) {
    using P = Pol<F32>;
    const int t   = threadIdx.x;
    const int bn0 = blockIdx.x * NB;
    const int b   = bn0 >> 9;                  // 512 nodes per batch
    const int l   = t & 63;
    const int w   = t >> 6;                    // wave 0..7
    const int lo  = l & 15;
    const int hi  = l >> 4;

    // ---- P1: self rows + neighbor lists + wsrc/wdst staging (512 threads)
    {
        const int r = t >> 5, c0 = (t & 31) * 4;
        const float4 v = P::ld4(h, (bn0 + r) * 128 + c0);
        *(float4*)&s.hs[r][c0] = v;
    }
    if (t < 256) {
        const int r = t >> 4, m = t & 15;
        s.nls[r][m]  = n_list[(bn0 + r) * M_ + m] & (N_ - 1);
        s.adjs[r][m] = adj[(bn0 + r) * M_ + m];
        *(float4*)&s.u.wsd[0][t * 4] = *(const float4*)(wsrc + t * 4);
    } else {
        const int i = t - 256;
        *(float4*)&s.u.wsd[1][i * 4] = *(const float4*)(wdst + i * 4);
    }
    __syncthreads();

    // ---- P2: scores = mask(leaky(s_src + s_dst[nl])), in-block, de-duplicated.
    {
        const int p = t >> 1, sub = t & 1;
        const int r = p >> 4, m = p & 15;          // edge (r,m)
        const int nbr  = s.nls[r][m];
        const int gbase = (b * N_ + nbr) * 128 + sub * 64;
        const int lbase = sub * 64;

        // dst dots: 2 threads per edge, 8 heads inline, 64 elems each.
        float accD[8];
        #pragma unroll
        for (int hh = 0; hh < 8; ++hh) accD[hh] = 0.f;
        #pragma unroll 4
        for (int c = 0; c < 64; c += 4) {
            const float4 hv = P::ld4(h, gbase + c);
            #pragma unroll
            for (int hh = 0; hh < 8; ++hh) {
                const float4 wdv = *(const float4*)&s.u.wsd[1][hh * 128 + lbase + c];
                accD[hh] += hv.x * wdv.x + hv.y * wdv.y + hv.z * wdv.z + hv.w * wdv.w;
            }
        }
        #pragma unroll
        for (int hh = 0; hh < 8; ++hh) accD[hh] += __shfl_xor(accD[hh], 1);

        // src dots: once per (node, head) — threads 0..255, 64 MACs each.
        if (t < 256) {
            const int r2  = t >> 4, hh2 = (t >> 1) & 7;   // sub = t&1 pairs
            const float* hr = &s.hs[r2][lbase];
            const float* wr = &s.u.wsd[0][hh2 * 128 + lbase];
            float accS = 0.f;
            #pragma unroll 4
            for (int c = 0; c < 64; c += 4) {
                const float4 sv = *(const float4*)(hr + c);
                const float4 wv = *(const float4*)(wr + c);
                accS += sv.x * wv.x + sv.y * wv.y + sv.z * wv.z + sv.w * wv.w;
            }
            accS += __shfl_xor(accS, 1);
            if (sub == 0) s.ssrc[r2][hh2] = accS;
        }
        __syncthreads();

        if (sub == 0) {
            const int amask = s.adjs[r][m];
            float sc[8];
            #pragma unroll
            for (int hh = 0; hh < 8; ++hh) {
                float x = s.ssrc[r][hh] + accD[hh];
                x = x > 0.f ? x : 0.2f * x;    // leaky_relu BEFORE mask (ref order)
                if (amask == 0) x = -1e9f;
                sc[hh] = x;
            }
            *(float4*)&s.v.attn[r][m][0] = make_float4(sc[0], sc[1], sc[2], sc[3]);
            *(float4*)&s.v.attn[r][m][4] = make_float4(sc[4], sc[5], sc[6], sc[7]);
        }
    }
    __syncthreads();

    // ---- P3: softmax over m   (128 threads)
    if (t < NB * 8) {
        const int r = t >> 3, hh = t & 7;
        float mx = -3.4e38f;
        #pragma unroll
        for (int m = 0; m < 16; ++m) mx = fmaxf(mx, s.v.attn[r][m][hh]);
        float ex[16], sum = 0.f;
        #pragma unroll
        for (int m = 0; m < 16; ++m) { ex[m] = __expf(s.v.attn[r][m][hh] - mx); sum += ex[m]; }
        const float inv = 1.f / sum;
        #pragma unroll
        for (int m = 0; m < 16; ++m) s.v.attn[r][m][hh] = ex[m] * inv;
    }
    __syncthreads();

    // ---- P4: Z[r][hh][d] = sum_m attn[r][m][hh] * h[nl[r][m]][d]
    //      512 threads: 32 threads/node, 4 d each.  (f16, swizzled)
    {
        const int r = t >> 5, dc = t & 31, d0 = dc * 4;
        float z[8][4];
        #pragma unroll
        for (int hh = 0; hh < 8; ++hh)
            #pragma unroll
            for (int jj = 0; jj < 4; ++jj) z[hh][jj] = 0.f;
        #pragma unroll 4
        for (int m = 0; m < 16; ++m) {
            const int nbr = s.nls[r][m];
            const float4 hv = P::ld4(h, (b * N_ + nbr) * 128 + d0);
            const float hv4[4] = { hv.x, hv.y, hv.z, hv.w };
            const float4 a0 = *(const float4*)&s.v.attn[r][m][0];
            const float4 a1 = *(const float4*)&s.v.attn[r][m][4];
            const float av[8] = { a0.x, a0.y, a0.z, a0.w, a1.x, a1.y, a1.z, a1.w };
            #pragma unroll
            for (int hh = 0; hh < 8; ++hh)
                #pragma unroll
                for (int jj = 0; jj < 4; ++jj) z[hh][jj] += av[hh] * hv4[jj];
        }
        char* zb = (char*)&s.u.Zh[0][0] + r * 2048;
        const int xo = (r & 7) << 4;
        #pragma unroll
        for (int hh = 0; hh < 8; ++hh) {
            f16x4 vv;
            #pragma unroll
            for (int jj = 0; jj < 4; ++jj) vv[jj] = (_Float16)z[hh][jj];
            *(f16x4*)(zb + ((hh * 256 + dc * 8) ^ xo)) = vv;
        }
    }
    __syncthreads();

    // ---- G1: yln = Zh @ WeffT^T + hs   (MFMA 16x16x16, K=1024; 8 waves x 16 cols)
    {
        const char* za  = (const char*)&s.u.Zh[0][0] + lo * 2048;
        const int   xo  = (lo & 7) << 4;
        const char* wb0 = (const char*)(WeffT + (size_t)(w * 16 + lo) * 1024);
        f32x4 acc0 = {0.f, 0.f, 0.f, 0.f};
        #pragma unroll 8
        for (int ks = 0; ks < 64; ++ks) {
            const int kb = ks * 32 + hi * 8;           // byte offset of k = ks*16 + hi*4
            const f16x4 a  = *(const f16x4*)(za + (kb ^ xo));
            const f16x4 b0 = *(const f16x4*)(wb0 + kb);
            acc0 = __builtin_amdgcn_mfma_f32_16x16x16f16(a, b0, acc0, 0, 0, 0);
        }
        const int o0 = w * 16 + lo;
        #pragma unroll
        for (int q = 0; q < 4; ++q) {
            const int rr = hi * 4 + q;
            s.v.yln[rr][o0] = acc0[q] + s.hs[rr][o0];
        }
    }
    __syncthreads();

    // ---- LN1 -> ts (f32, padded rows). 16 threads per row (256 threads).
    if (t < NB * 16) {
        const int r = t >> 4, j0 = (t & 15) * 8;
        const float4 x0 = *(const float4*)&s.v.yln[r][j0];
        const float4 x1 = *(const float4*)&s.v.yln[r][j0 + 4];
        const float x[8] = { x0.x, x0.y, x0.z, x0.w, x1.x, x1.y, x1.z, x1.w };
        float sm = 0.f, ss = 0.f;
        #pragma unroll
        for (int j = 0; j < 8; ++j) { sm += x[j]; ss += x[j] * x[j]; }
        #pragma unroll
        for (int off = 8; off > 0; off >>= 1) {
            sm += __shfl_xor(sm, off);
            ss += __shfl_xor(ss, off);
        }
        const float mu   = sm * (1.f / 128.f);
        const float var  = ss * (1.f / 128.f) - mu * mu;
        const float rstd = rsqrtf(var + 1e-5f);
        float gv[8], bv[8];
        P::ld8(g1, j0, gv);
        P::ld8(bb1, j0, bv);
        #pragma unroll
        for (int j = 0; j < 8; ++j)
            s.u.ff.ts[r][j0 + j] = (x[j] - mu) * rstd * gv[j] + bv[j];
    }
    __syncthreads();

    // ---- FF1: us = relu(ts @ w1 + b1)  (MFMA; 8 waves x 32 cols; K=128)
    {
        f32x4 acc[2] = { {0.f,0.f,0.f,0.f}, {0.f,0.f,0.f,0.f} };
        #pragma unroll
        for (int ks = 0; ks < 8; ++ks) {
            const int k = ks * 16 + hi * 4;
            const float4 tv = *(const float4*)&s.u.ff.ts[lo][k];
            f16x4 a;
            a[0] = (_Float16)tv.x; a[1] = (_Float16)tv.y;
            a[2] = (_Float16)tv.z; a[3] = (_Float16)tv.w;
            #pragma unroll
            for (int nt = 0; nt < 2; ++nt) {
                const int o = w * 32 + nt * 16 + lo;
                f16x4 bb;
                #pragma unroll
                for (int j = 0; j < 4; ++j) bb[j] = (_Float16)P::ld(w1, (k + j) * 256 + o);
                acc[nt] = __builtin_amdgcn_mfma_f32_16x16x16f16(a, bb, acc[nt], 0, 0, 0);
            }
        }
        #pragma unroll
        for (int nt = 0; nt < 2; ++nt) {
            const int o = w * 32 + nt * 16 + lo;
            const float bias = P::ld(fb1, o);
            #pragma unroll
            for (int q = 0; q < 4; ++q)
                s.u.ff.us[hi * 4 + q][o] = (_Float16)fmaxf(acc[nt][q] + bias, 0.f);
        }
    }
    __syncthreads();

    // ---- FF2: ys = us @ w2 + b2 + ts  (MFMA; 8 waves x 16 cols; K=256)
    {
        const int o0 = w * 16 + lo;
        f32x4 acc = {0.f, 0.f, 0.f, 0.f};
        #pragma unroll
        for (int ks = 0; ks < 16; ++ks) {
            const int k = ks * 16 + hi * 4;
            const f16x4 a = *(const f16x4*)&s.u.ff.us[lo][k];
            f16x4 bb;
            #pragma unroll
            for (int j = 0; j < 4; ++j) bb[j] = (_Float16)P::ld(w2, (k + j) * 128 + o0);
            acc = __builtin_amdgcn_mfma_f32_16x16x16f16(a, bb, acc, 0, 0, 0);
        }
        const float bias = P::ld(fb2, o0);
        #pragma unroll
        for (int q = 0; q < 4; ++q) {
            const int rr = hi * 4 + q;
            s.u.ff.ys[rr][o0] = acc[q] + bias + s.u.ff.ts[rr][o0];
        }
    }
    __syncthreads();

    // ---- LN2 -> out. 16 threads per row (256 threads).
    if (t < NB * 16) {
        const int r = t >> 4, j0 = (t & 15) * 8;
        const float4 x0 = *(const float4*)&s.u.ff.ys[r][j0];
        const float4 x1 = *(const float4*)&s.u.ff.ys[r][j0 + 4];
        const float x[8] = { x0.x, x0.y, x0.z, x0.w, x1.x, x1.y, x1.z, x1.w };
        float sm = 0.f, ss = 0.f;
        #pragma unroll
        for (int j = 0; j < 8; ++j) { sm += x[j]; ss += x[j] * x[j]; }
        #pragma unroll
        for (int off = 8; off > 0; off >>= 1) {
            sm += __shfl_xor(sm, off);
            ss += __shfl_xor(ss, off);
        }
        const float mu   = sm * (1.f / 128.f);
        const float var  = ss * (1.f / 128.f) - mu * mu;
        const float rstd = rsqrtf(var + 1e-5f);
        float gv[8], bv[8], o8[8];
        P::ld8(g2, j0, gv);
        P::ld8(bb2, j0, bv);
        #pragma unroll
        for (int j = 0; j < 8; ++j) o8[j] = (x[j] - mu) * rstd * gv[j] + bv[j];
        P::st8(out, (long)(bn0 + r) * 128 + j0, o8);
    }
}

__global__ __launch_bounds__(512) void k_gat(
        const void* __restrict__ h,
        const int*  __restrict__ adj,
        const int*  __restrict__ n_list,
        const float* __restrict__ wsrc,
        const float* __restrict__ wdst,
        const _Float16* __restrict__ WeffT,
        const void* __restrict__ g1, const void* __restrict__ bb1,
        const void* __restrict__ w1, const void* __restrict__ fb1,
        const void* __restrict__ w2, const void* __restrict__ fb2,
        const void* __restrict__ g2, const void* __restrict__ bb2,
        void* __restrict__ out) {
    __shared__ Smem s;
    if (probe_is_f32(h))
        gat_body<true >(s, h, adj, n_list, wsrc, wdst, WeffT,
                        g1, bb1, w1, fb1, w2, fb2, g2, bb2, out);
    else
        gat_body<false>(s, h, adj, n_list, wsrc, wdst, WeffT,
                        g1, bb1, w1, fb1, w2, fb2, g2, bb2, out);
}

// ---------------------------------------------------------------------------
extern "C" void kernel_launch(void* const* d_in, const int* in_sizes, int n_in,
                              void* d_out, int out_size, void* d_ws, size_t ws_size,
                              hipStream_t stream) {
    (void)in_sizes; (void)n_in; (void)out_size; (void)ws_size;

    // ws layout (bytes):
    //   wsrc   [     0,   4096)  f32[1024]
    //   wdst   [  4096,   8192)  f32[1024]
    //   WeffT  [  8192, 270336)  f16[128][1024]
    char* wsb = (char*)d_ws;
    float*     wsrc  = (float*)(wsb);
    float*     wdst  = (float*)(wsb + 4096);
    _Float16*  WeffT = (_Float16*)(wsb + 8192);

    k0<<<520, 256, 0, stream>>>(d_in[3], d_in[6], d_in[4], d_in[5], d_in[0],
                                wsrc, wdst, WeffT);
    k_gat<<<BN_ / NB, 512, 0, stream>>>(
        d_in[0], (const int*)d_in[1], (const int*)d_in[2], wsrc, wdst, WeffT,
        d_in[7], d_in[8], d_in[9], d_in[10], d_in[11], d_in[12],
        d_in[13], d_in[14], d_out);
}

// Round 13
// 157.215 us; speedup vs baseline: 1.0960x; 1.0102x over previous
//
#include <hip/hip_runtime.h>
#include <hip/hip_bf16.h>

// Problem constants
#define B_  16
#define N_  512
#define M_  16
#define H_  8
#define D_  128
#define BN_ 8192   // B_*N_
#define NB  16     // nodes per block in main kernel

typedef __attribute__((ext_vector_type(4))) float          f32x4;
typedef __attribute__((ext_vector_type(4))) _Float16       f16x4;
typedef __attribute__((ext_vector_type(8))) unsigned short u16x8;
typedef __attribute__((ext_vector_type(8))) _Float16       f16x8;

static __device__ __forceinline__ float bf2f(__hip_bfloat16 x) { return __bfloat162float(x); }
static __device__ __forceinline__ unsigned short f2bu(float x) {
    __hip_bfloat16 b = __float2bfloat16(x);
    return *reinterpret_cast<unsigned short*>(&b);
}
static __device__ __forceinline__ float bu2f(unsigned short u) {
    return __uint_as_float(((unsigned int)u) << 16);
}

// Load/store policy: interpret float tensors as f32 or bf16.
template <bool F32>
struct Pol {
    static __device__ __forceinline__ float ld(const void* p, int i) {
        if constexpr (F32) return ((const float*)p)[i];
        else               return bf2f(((const __hip_bfloat16*)p)[i]);
    }
    static __device__ __forceinline__ float4 ld4(const void* p, int i) {  // i%4==0
        if constexpr (F32) return *(const float4*)((const float*)p + i);
        else {
            const ushort4 u = *(const ushort4*)((const unsigned short*)p + i);
            return make_float4(bu2f(u.x), bu2f(u.y), bu2f(u.z), bu2f(u.w));
        }
    }
    static __device__ __forceinline__ void ld8(const void* p, long i, float* v) {  // i%8==0
        if constexpr (F32) {
            const float4 a = *(const float4*)((const float*)p + i);
            const float4 b = *(const float4*)((const float*)p + i + 4);
            v[0]=a.x; v[1]=a.y; v[2]=a.z; v[3]=a.w;
            v[4]=b.x; v[5]=b.y; v[6]=b.z; v[7]=b.w;
        } else {
            const u16x8 u = *(const u16x8*)((const unsigned short*)p + i);
            #pragma unroll
            for (int j = 0; j < 8; ++j) v[j] = bu2f(u[j]);
        }
    }
    static __device__ __forceinline__ void st8(void* p, long i, const float* v) {  // i%8==0
        if constexpr (F32) {
            *(float4*)((float*)p + i)     = make_float4(v[0], v[1], v[2], v[3]);
            *(float4*)((float*)p + i + 4) = make_float4(v[4], v[5], v[6], v[7]);
        } else {
            u16x8 u;
            #pragma unroll
            for (int j = 0; j < 8; ++j) u[j] = f2bu(v[j]);
            *(u16x8*)((unsigned short*)p + i) = u;
        }
    }
};

// Dtype probe (verbatim): f32 buffers read as bf16 at even index give
// random-exponent garbage; genuine bf16 stays small.
static __device__ __forceinline__ bool probe_is_f32(const void* h) {
    bool is_f32 = false;
    const __hip_bfloat16* hb = (const __hip_bfloat16*)h;
    for (int i = 0; i < 128; ++i) {
        const float v = bf2f(hb[2 * i]);
        if (!(fabsf(v) < 1e4f)) is_f32 = true;
    }
    return is_f32;
}

// ---------------------------------------------------------------------------
// K0 (prep, grid 520):  [byte-identical to passing rounds 5/11/12]
//   blk <  512 : WeffT[o][hd] = f16( sum_e W[hd][e] * Wo[(h*128+e)][o] )
//   blk >= 512 : wsrc/wdst[h][d] = sum_e W[h][d][e] * a_{src,dst}[h][e]  (f32)
// ---------------------------------------------------------------------------
template <bool F32>
static __device__ __forceinline__ void k0_body(
        const void* __restrict__ W,  const void* __restrict__ Wo,
        const void* __restrict__ a_src, const void* __restrict__ a_dst,
        float* __restrict__ wsrc, float* __restrict__ wdst,
        _Float16* __restrict__ WeffT, float* wrow /* shared [2*128] */) {
    using P = Pol<F32>;
    const int blk = blockIdx.x;
    const int t   = threadIdx.x;
    if (blk < 512) {
        const int half = t >> 7, o = t & 127;
        const int hd = blk * 2 + half;               // hd = h*128 + d
        wrow[half * 128 + o] = P::ld(W, hd * 128 + o);
        __syncthreads();
        const int hh = hd >> 7;
        float acc = 0.f;
        #pragma unroll 8
        for (int e = 0; e < 128; ++e)
            acc += wrow[half * 128 + e] * P::ld(Wo, (hh * 128 + e) * 128 + o);
        WeffT[(size_t)o * 1024 + hd] = (_Float16)acc;
    } else {
        const int hh = blk - 512;
        const int which = t >> 7, d = t & 127;
        const void* av = which ? a_dst : a_src;
        const int wbase = hh * (D_ * D_) + d * 128;
        float acc = 0.f;
        #pragma unroll 8
        for (int e = 0; e < 128; e += 4) {
            const float4 wv = P::ld4(W, wbase + e);
            const float4 aa = P::ld4(av, hh * 128 + e);
            acc += wv.x * aa.x + wv.y * aa.y + wv.z * aa.z + wv.w * aa.w;
        }
        (which ? wdst : wsrc)[hh * 128 + d] = acc;
    }
}

__global__ __launch_bounds__(256) void k0(
        const void* W, const void* Wo, const void* a_src, const void* a_dst,
        const void* h, float* wsrc, float* wdst, _Float16* WeffT) {
    __shared__ float wrow[2 * 128];
    if (probe_is_f32(h)) k0_body<true >(W, Wo, a_src, a_dst, wsrc, wdst, WeffT, wrow);
    else                 k0_body<false>(W, Wo, a_src, a_dst, wsrc, wdst, WeffT, wrow);
}

// ---------------------------------------------------------------------------
// Main fused kernel. 16 nodes/block, 512 threads (8 waves), grid 512.
// Round-12 structure (passed, 158.82) with LDS BANK-CONFLICT PADDING:
//   hs/yln/ys/attn rows and wsd head-rows padded to 132 floats so row
//   strides are != 0 mod 32 banks (fixes the 8/16-way conflicts in P2/P3).
// MFMA layout (proven): A lane(lo,hi) reg j = A[lo][4*hi+j]; B = B[4*hi+j][lo];
// D reg q -> row 4*hi+q, col lo.
// ---------------------------------------------------------------------------
struct __align__(16) Smem {
    union {
        _Float16 Zh[NB][1024];                 // 32768   P4 -> G1 (f16, swizzled)
        float    wsd[2][1056];                 // 8448    [which][hh*132 + c]
        struct {
            float    ts[NB][132];              // 8448    LN1 -> FF1/FF2 (padded)
            _Float16 us[NB][260];              // 8320    FF1 -> FF2 (padded)
            float    ys[NB][132];              // 8448    FF2 -> LN2 (padded)
        } ff;
    } u;
    float hs[NB][132];                         // 8448    residual + src-dot (padded)
    union {
        float attn[NB][132];                   // 8448    [r][m*8+hh] (padded stride)
        float yln[NB][132];                    // 8448    G1 -> LN1 (padded)
    } v;
    int   nls[NB][16];                         // 1024
    int   adjs[NB][16];                        // 1024
    float ssrc[NB][8];                         // 512
};

template <bool F32>
static __device__ __forceinline__ void gat_body(
        Smem& s,
        const void* __restrict__ h,
        const int*  __restrict__ adj,
        const int*  __restrict__ n_list,
        const float* __restrict__ wsrc,
        const float* __restrict__ wdst,
        const _Float16* __restrict__ WeffT,
        const void* __restrict__ g1, const void* __restrict__ bb1,
        const void* __restrict__ w1, const void* __restrict__ fb1,
        const void* __restrict__ w2, const void* __restrict__ fb2,
        const void* __restrict__ g2, const void* __restrict__ bb2,
        void* __restrict__ out) {
    using P = Pol<F32>;
    const int t   = threadIdx.x;
    const int bn0 = blockIdx.x * NB;
    const int b   = bn0 >> 9;                  // 512 nodes per batch
    const int l   = t & 63;
    const int w   = t >> 6;                    // wave 0..7
    const int lo  = l & 15;
    const int hi  = l >> 4;

    // ---- P1: self rows + neighbor lists + wsrc/wdst staging (512 threads)
    {
        const int r = t >> 5, c0 = (t & 31) * 4;
        const float4 v = P::ld4(h, (bn0 + r) * 128 + c0);
        *(float4*)&s.hs[r][c0] = v;
    }
    if (t < 256) {
        const int r = t >> 4, m = t & 15;
        s.nls[r][m]  = n_list[(bn0 + r) * M_ + m] & (N_ - 1);
        s.adjs[r][m] = adj[(bn0 + r) * M_ + m];
        const int hh0 = t >> 5, c0 = (t & 31) * 4;
        *(float4*)&s.u.wsd[0][hh0 * 132 + c0] = *(const float4*)(wsrc + t * 4);
    } else {
        const int i = t - 256;
        const int hh0 = i >> 5, c0 = (i & 31) * 4;
        *(float4*)&s.u.wsd[1][hh0 * 132 + c0] = *(const float4*)(wdst + i * 4);
    }
    __syncthreads();

    // ---- P2: scores = mask(leaky(s_src + s_dst[nl])), in-block, de-duplicated.
    {
        const int p = t >> 1, sub = t & 1;
        const int r = p >> 4, m = p & 15;          // edge (r,m)
        const int nbr  = s.nls[r][m];
        const int gbase = (b * N_ + nbr) * 128 + sub * 64;
        const int lbase = sub * 64;

        // dst dots: 2 threads per edge, 8 heads inline, 64 elems each.
        float accD[8];
        #pragma unroll
        for (int hh = 0; hh < 8; ++hh) accD[hh] = 0.f;
        #pragma unroll 4
        for (int c = 0; c < 64; c += 4) {
            const float4 hv = P::ld4(h, gbase + c);
            #pragma unroll
            for (int hh = 0; hh < 8; ++hh) {
                const float4 wdv = *(const float4*)&s.u.wsd[1][hh * 132 + lbase + c];
                accD[hh] += hv.x * wdv.x + hv.y * wdv.y + hv.z * wdv.z + hv.w * wdv.w;
            }
        }
        #pragma unroll
        for (int hh = 0; hh < 8; ++hh) accD[hh] += __shfl_xor(accD[hh], 1);

        // src dots: once per (node, head) — threads 0..255, 64 MACs each.
        if (t < 256) {
            const int r2  = t >> 4, hh2 = (t >> 1) & 7;   // sub = t&1 pairs
            const float* hr = &s.hs[r2][lbase];
            const float* wr = &s.u.wsd[0][hh2 * 132 + lbase];
            float accS = 0.f;
            #pragma unroll 4
            for (int c = 0; c < 64; c += 4) {
                const float4 sv = *(const float4*)(hr + c);
                const float4 wv = *(const float4*)(wr + c);
                accS += sv.x * wv.x + sv.y * wv.y + sv.z * wv.z + sv.w * wv.w;
            }
            accS += __shfl_xor(accS, 1);
            if (sub == 0) s.ssrc[r2][hh2] = accS;
        }
        __syncthreads();

        if (sub == 0) {
            const int amask = s.adjs[r][m];
            float sc[8];
            #pragma unroll
            for (int hh = 0; hh < 8; ++hh) {
                float x = s.ssrc[r][hh] + accD[hh];
                x = x > 0.f ? x : 0.2f * x;    // leaky_relu BEFORE mask (ref order)
                if (amask == 0) x = -1e9f;
                sc[hh] = x;
            }
            *(float4*)&s.v.attn[r][m * 8]     = make_float4(sc[0], sc[1], sc[2], sc[3]);
            *(float4*)&s.v.attn[r][m * 8 + 4] = make_float4(sc[4], sc[5], sc[6], sc[7]);
        }
    }
    __syncthreads();

    // ---- P3: softmax over m   (128 threads)
    if (t < NB * 8) {
        const int r = t >> 3, hh = t & 7;
        float mx = -3.4e38f;
        #pragma unroll
        for (int m = 0; m < 16; ++m) mx = fmaxf(mx, s.v.attn[r][m * 8 + hh]);
        float ex[16], sum = 0.f;
        #pragma unroll
        for (int m = 0; m < 16; ++m) { ex[m] = __expf(s.v.attn[r][m * 8 + hh] - mx); sum += ex[m]; }
        const float inv = 1.f / sum;
        #pragma unroll
        for (int m = 0; m < 16; ++m) s.v.attn[r][m * 8 + hh] = ex[m] * inv;
    }
    __syncthreads();

    // ---- P4: Z[r][hh][d] = sum_m attn[r][m][hh] * h[nl[r][m]][d]
    //      512 threads: 32 threads/node, 4 d each.  (f16, swizzled)
    {
        const int r = t >> 5, dc = t & 31, d0 = dc * 4;
        float z[8][4];
        #pragma unroll
        for (int hh = 0; hh < 8; ++hh)
            #pragma unroll
            for (int jj = 0; jj < 4; ++jj) z[hh][jj] = 0.f;
        #pragma unroll 4
        for (int m = 0; m < 16; ++m) {
            const int nbr = s.nls[r][m];
            const float4 hv = P::ld4(h, (b * N_ + nbr) * 128 + d0);
            const float hv4[4] = { hv.x, hv.y, hv.z, hv.w };
            const float4 a0 = *(const float4*)&s.v.attn[r][m * 8];
            const float4 a1 = *(const float4*)&s.v.attn[r][m * 8 + 4];
            const float av[8] = { a0.x, a0.y, a0.z, a0.w, a1.x, a1.y, a1.z, a1.w };
            #pragma unroll
            for (int hh = 0; hh < 8; ++hh)
                #pragma unroll
                for (int jj = 0; jj < 4; ++jj) z[hh][jj] += av[hh] * hv4[jj];
        }
        char* zb = (char*)&s.u.Zh[0][0] + r * 2048;
        const int xo = (r & 7) << 4;
        #pragma unroll
        for (int hh = 0; hh < 8; ++hh) {
            f16x4 vv;
            #pragma unroll
            for (int jj = 0; jj < 4; ++jj) vv[jj] = (_Float16)z[hh][jj];
            *(f16x4*)(zb + ((hh * 256 + dc * 8) ^ xo)) = vv;
        }
    }
    __syncthreads();

    // ---- G1: yln = Zh @ WeffT^T + hs   (MFMA 16x16x16, K=1024; 8 waves x 16 cols)
    {
        const char* za  = (const char*)&s.u.Zh[0][0] + lo * 2048;
        const int   xo  = (lo & 7) << 4;
        const char* wb0 = (const char*)(WeffT + (size_t)(w * 16 + lo) * 1024);
        f32x4 acc0 = {0.f, 0.f, 0.f, 0.f};
        #pragma unroll 8
        for (int ks = 0; ks < 64; ++ks) {
            const int kb = ks * 32 + hi * 8;           // byte offset of k = ks*16 + hi*4
            const f16x4 a  = *(const f16x4*)(za + (kb ^ xo));
            const f16x4 b0 = *(const f16x4*)(wb0 + kb);
            acc0 = __builtin_amdgcn_mfma_f32_16x16x16f16(a, b0, acc0, 0, 0, 0);
        }
        const int o0 = w * 16 + lo;
        #pragma unroll
        for (int q = 0; q < 4; ++q) {
            const int rr = hi * 4 + q;
            s.v.yln[rr][o0] = acc0[q] + s.hs[rr][o0];
        }
    }
    __syncthreads();

    // ---- LN1 -> ts (f32, padded rows). 16 threads per row (256 threads).
    if (t < NB * 16) {
        const int r = t >> 4, j0 = (t & 15) * 8;
        const float4 x0 = *(const float4*)&s.v.yln[r][j0];
        const float4 x1 = *(const float4*)&s.v.yln[r][j0 + 4];
        const float x[8] = { x0.x, x0.y, x0.z, x0.w, x1.x, x1.y, x1.z, x1.w };
        float sm = 0.f, ss = 0.f;
        #pragma unroll
        for (int j = 0; j < 8; ++j) { sm += x[j]; ss += x[j] * x[j]; }
        #pragma unroll
        for (int off = 8; off > 0; off >>= 1) {
            sm += __shfl_xor(sm, off);
            ss += __shfl_xor(ss, off);
        }
        const float mu   = sm * (1.f / 128.f);
        const float var  = ss * (1.f / 128.f) - mu * mu;
        const float rstd = rsqrtf(var + 1e-5f);
        float gv[8], bv[8];
        P::ld8(g1, j0, gv);
        P::ld8(bb1, j0, bv);
        #pragma unroll
        for (int j = 0; j < 8; ++j)
            s.u.ff.ts[r][j0 + j] = (x[j] - mu) * rstd * gv[j] + bv[j];
    }
    __syncthreads();

    // ---- FF1: us = relu(ts @ w1 + b1)  (MFMA; 8 waves x 32 cols; K=128)
    {
        f32x4 acc[2] = { {0.f,0.f,0.f,0.f}, {0.f,0.f,0.f,0.f} };
        #pragma unroll
        for (int ks = 0; ks < 8; ++ks) {
            const int k = ks * 16 + hi * 4;
            const float4 tv = *(const float4*)&s.u.ff.ts[lo][k];
            f16x4 a;
            a[0] = (_Float16)tv.x; a[1] = (_Float16)tv.y;
            a[2] = (_Float16)tv.z; a[3] = (_Float16)tv.w;
            #pragma unroll
            for (int nt = 0; nt < 2; ++nt) {
                const int o = w * 32 + nt * 16 + lo;
                f16x4 bb;
                #pragma unroll
                for (int j = 0; j < 4; ++j) bb[j] = (_Float16)P::ld(w1, (k + j) * 256 + o);
                acc[nt] = __builtin_amdgcn_mfma_f32_16x16x16f16(a, bb, acc[nt], 0, 0, 0);
            }
        }
        #pragma unroll
        for (int nt = 0; nt < 2; ++nt) {
            const int o = w * 32 + nt * 16 + lo;
            const float bias = P::ld(fb1, o);
            #pragma unroll
            for (int q = 0; q < 4; ++q)
                s.u.ff.us[hi * 4 + q][o] = (_Float16)fmaxf(acc[nt][q] + bias, 0.f);
        }
    }
    __syncthreads();

    // ---- FF2: ys = us @ w2 + b2 + ts  (MFMA; 8 waves x 16 cols; K=256)
    {
        const int o0 = w * 16 + lo;
        f32x4 acc = {0.f, 0.f, 0.f, 0.f};
        #pragma unroll
        for (int ks = 0; ks < 16; ++ks) {
            const int k = ks * 16 + hi * 4;
            const f16x4 a = *(const f16x4*)&s.u.ff.us[lo][k];
            f16x4 bb;
            #pragma unroll
            for (int j = 0; j < 4; ++j) bb[j] = (_Float16)P::ld(w2, (k + j) * 128 + o0);
            acc = __builtin_amdgcn_mfma_f32_16x16x16f16(a, bb, acc, 0, 0, 0);
        }
        const float bias = P::ld(fb2, o0);
        #pragma unroll
        for (int q = 0; q < 4; ++q) {
            const int rr = hi * 4 + q;
            s.u.ff.ys[rr][o0] = acc[q] + bias + s.u.ff.ts[rr][o0];
        }
    }
    __syncthreads();

    // ---- LN2 -> out. 16 threads per row (256 threads).
    if (t < NB * 16) {
        const int r = t >> 4, j0 = (t & 15) * 8;
        const float4 x0 = *(const float4*)&s.u.ff.ys[r][j0];
        const float4 x1 = *(const float4*)&s.u.ff.ys[r][j0 + 4];
        const float x[8] = { x0.x, x0.y, x0.z, x0.w, x1.x, x1.y, x1.z, x1.w };
        float sm = 0.f, ss = 0.f;
        #pragma unroll
        for (int j = 0; j < 8; ++j) { sm += x[j]; ss += x[j] * x[j]; }
        #pragma unroll
        for (int off = 8; off > 0; off >>= 1) {
            sm += __shfl_xor(sm, off);
            ss += __shfl_xor(ss, off);
        }
        const float mu   = sm * (1.f / 128.f);
        const float var  = ss * (1.f / 128.f) - mu * mu;
        const float rstd = rsqrtf(var + 1e-5f);
        float gv[8], bv[8], o8[8];
        P::ld8(g2, j0, gv);
        P::ld8(bb2, j0, bv);
        #pragma unroll
        for (int j = 0; j < 8; ++j) o8[j] = (x[j] - mu) * rstd * gv[j] + bv[j];
        P::st8(out, (long)(bn0 + r) * 128 + j0, o8);
    }
}

__global__ __launch_bounds__(512) void k_gat(
        const void* __restrict__ h,
        const int*  __restrict__ adj,
        const int*  __restrict__ n_list,
        const float* __restrict__ wsrc,
        const float* __restrict__ wdst,
        const _Float16* __restrict__ WeffT,
        const void* __restrict__ g1, const void* __restrict__ bb1,
        const void* __restrict__ w1, const void* __restrict__ fb1,
        const void* __restrict__ w2, const void* __restrict__ fb2,
        const void* __restrict__ g2, const void* __restrict__ bb2,
        void* __restrict__ out) {
    __shared__ Smem s;
    if (probe_is_f32(h))
        gat_body<true >(s, h, adj, n_list, wsrc, wdst, WeffT,
                        g1, bb1, w1, fb1, w2, fb2, g2, bb2, out);
    else
        gat_body<false>(s, h, adj, n_list, wsrc, wdst, WeffT,
                        g1, bb1, w1, fb1, w2, fb2, g2, bb2, out);
}

// ---------------------------------------------------------------------------
extern "C" void kernel_launch(void* const* d_in, const int* in_sizes, int n_in,
                              void* d_out, int out_size, void* d_ws, size_t ws_size,
                              hipStream_t stream) {
    (void)in_sizes; (void)n_in; (void)out_size; (void)ws_size;

    // ws layout (bytes):
    //   wsrc   [     0,   4096)  f32[1024]
    //   wdst   [  4096,   8192)  f32[1024]
    //   WeffT  [  8192, 270336)  f16[128][1024]
    char* wsb = (char*)d_ws;
    float*     wsrc  = (float*)(wsb);
    float*     wdst  = (float*)(wsb + 4096);
    _Float16*  WeffT = (_Float16*)(wsb + 8192);

    k0<<<520, 256, 0, stream>>>(d_in[3], d_in[6], d_in[4], d_in[5], d_in[0],
                                wsrc, wdst, WeffT);
    k_gat<<<BN_ / NB, 512, 0, stream>>>(
        d_in[0], (const int*)d_in[1], (const int*)d_in[2], wsrc, wdst, WeffT,
        d_in[7], d_in[8], d_in[9], d_in[10], d_in[11], d_in[12],
        d_in[13], d_in[14], d_out);
}